// Round 6
// baseline (75.863 us; speedup 1.0000x reference)
//
#include <hip/hip_runtime.h>
#include <hip/hip_bf16.h>

#define NB 128
#define NN 2048
#define DEG 16
#define EMBD 16
#define NL 4
#define OBSD 6154
#define HID 45
#define NOUT 15
#define KS 16
#define CH 385   // ceil(OBSD / KS)
#define LOG2E 1.44269504f

__device__ __forceinline__ float frcp(float v) { return __builtin_amdgcn_rcpf(v); }

__device__ __forceinline__ uint32_t pk_bf16(float a, float b) {
    uint32_t ua = __float_as_uint(a); ua += 0x7fffu + ((ua >> 16) & 1u);
    uint32_t ub = __float_as_uint(b); ub += 0x7fffu + ((ub >> 16) & 1u);
    return (ua >> 16) | (ub & 0xffff0000u);
}
__device__ __forceinline__ float lo_bf(uint32_t u) { return __uint_as_float(u << 16); }
__device__ __forceinline__ float hi_bf(uint32_t u) { return __uint_as_float(u & 0xffff0000u); }

__device__ __forceinline__ void ln4(const float* p, const float* g, const float* bb, float* o) {
    float m = 0.25f * (p[0] + p[1] + p[2] + p[3]);
    float var = 0.f;
#pragma unroll
    for (int j = 0; j < 4; ++j) { float d = p[j] - m; var += d * d; }
    var *= 0.25f;
    float rs = rsqrtf(var + 1e-5f);
#pragma unroll
    for (int j = 0; j < 4; ++j) o[j] = g[j] * (p[j] - m) * rs + bb[j];
}

// residual tail after attention message: Wo + LN1 + FFN + LN2 (updates hh in place)
__device__ __forceinline__ void node_tail(float* hh, const float* msg,
    const float* wo, const float* bol, const float* g1, const float* be1,
    const float* w1, const float* b1l, const float* w2, const float* b2l,
    const float* g2, const float* be2)
{
    float pre[4];
#pragma unroll
    for (int j = 0; j < 4; ++j) {
        float s = bol[j];
#pragma unroll
        for (int i = 0; i < 4; ++i) s += msg[i] * wo[i * 4 + j];
        pre[j] = hh[j] + s;
    }
    float hn[4];
    ln4(pre, g1, be1, hn);
    float mid[8];
#pragma unroll
    for (int j = 0; j < 8; ++j) {
        float s = b1l[j];
#pragma unroll
        for (int i = 0; i < 4; ++i) s += hn[i] * w1[i * 8 + j];
        mid[j] = fmaxf(s, 0.f);
    }
    float pre2[4];
#pragma unroll
    for (int j = 0; j < 4; ++j) {
        float s = b2l[j];
#pragma unroll
        for (int i = 0; i < 8; ++i) s += mid[i] * w2[i * 4 + j];
        pre2[j] = hn[j] + s;
    }
    ln4(pre2, g2, be2, hh);
}

// k,v projection of one node -> packed bf16 uint4
__device__ __forceinline__ uint4 kv_pack(const float* hh,
    const float* wk, const float* bkl, const float* wv, const float* bvl)
{
    float kk[4], vv[4];
#pragma unroll
    for (int j = 0; j < 4; ++j) {
        float sk = bkl[j], sv = bvl[j];
#pragma unroll
        for (int i = 0; i < 4; ++i) {
            sk += hh[i] * wk[i * 4 + j];
            sv += hh[i] * wv[i * 4 + j];
        }
        kk[j] = sk; vv[j] = sv;
    }
    return make_uint4(pk_bf16(kk[0], kk[1]), pk_bf16(kk[2], kk[3]),
                      pk_bf16(vv[0], vv[1]), pk_bf16(vv[2], vv[3]));
}

// ===================== embed + layer-0 kv projection =====================
__global__ __launch_bounds__(256) void embed_proj_kernel(
    const float* __restrict__ x, const float* __restrict__ We, const float* __restrict__ be,
    const float* __restrict__ Wk, const float* __restrict__ bk,
    const float* __restrict__ Wv, const float* __restrict__ bv,
    float4* __restrict__ h0, uint4* __restrict__ kv0)
{
    const int n = blockIdx.x * 256 + threadIdx.x;
    const float4* xr = reinterpret_cast<const float4*>(x + (size_t)n * EMBD);
    float xv[16];
#pragma unroll
    for (int t4 = 0; t4 < 4; ++t4) {
        float4 t = xr[t4];
        xv[t4 * 4 + 0] = t.x; xv[t4 * 4 + 1] = t.y;
        xv[t4 * 4 + 2] = t.z; xv[t4 * 4 + 3] = t.w;
    }
    float hh[4];
#pragma unroll
    for (int j = 0; j < 4; ++j) {
        float s = be[j];
#pragma unroll
        for (int i = 0; i < 16; ++i) s += xv[i] * We[i * 4 + j];
        hh[j] = s;
    }
    h0[n] = make_float4(hh[0], hh[1], hh[2], hh[3]);
    kv0[n] = kv_pack(hh, Wk, bk, Wv, bv);   // layer-0 weights passed directly
}

// ====== GAT layer l (l = 0..2): gather kv_l, tail -> h_{l+1}, proj kv_{l+1} ======
__global__ __launch_bounds__(256, 4) void gat_layer_kernel(
    const float4* __restrict__ hin, const uint4* __restrict__ kvin,
    float4* __restrict__ hout, uint4* __restrict__ kvout,
    const int* __restrict__ src, const int* __restrict__ agent_nodes, const int l,
    const float* __restrict__ Wq, const float* __restrict__ bq,
    const float* __restrict__ Wk, const float* __restrict__ bk,
    const float* __restrict__ Wv, const float* __restrict__ bv,
    const float* __restrict__ Wo, const float* __restrict__ bo,
    const float* __restrict__ ln1_g, const float* __restrict__ ln1_b,
    const float* __restrict__ W1, const float* __restrict__ b1,
    const float* __restrict__ W2, const float* __restrict__ b2,
    const float* __restrict__ ln2_g, const float* __restrict__ ln2_b)
{
    const int n = blockIdx.x * 256 + threadIdx.x;
    const int b = n >> 11, own = n & (NN - 1);

    // edge list (same for all graphs -> L2 hot)
    int su[16];
    {
        const int4* sp = reinterpret_cast<const int4*>(src + own * DEG);
#pragma unroll
        for (int t4 = 0; t4 < 4; ++t4) {
            int4 s4 = sp[t4];
            su[t4 * 4 + 0] = s4.x; su[t4 * 4 + 1] = s4.y;
            su[t4 * 4 + 2] = s4.z; su[t4 * 4 + 3] = s4.w;
        }
    }

    float4 h4 = hin[n];
    float hh[4] = {h4.x, h4.y, h4.z, h4.w};

    float q2[4];
    {
        const float* wq = Wq + l * 16; const float* bql = bq + l * 4;
#pragma unroll
        for (int j = 0; j < 4; ++j) {
            float sq = bql[j];
#pragma unroll
            for (int i = 0; i < 4; ++i) sq += hh[i] * wq[i * 4 + j];
            q2[j] = sq * LOG2E;
        }
    }

    const uint4* slab = kvin + (size_t)b * NN;
    float z[4] = {0.f, 0.f, 0.f, 0.f}, wa[4] = {0.f, 0.f, 0.f, 0.f};
#pragma unroll
    for (int c = 0; c < 2; ++c) {
        uint4 t[8];
#pragma unroll
        for (int i = 0; i < 8; ++i) t[i] = slab[su[c * 8 + i]];
#pragma unroll
        for (int i = 0; i < 8; ++i) {
            float p;
            p = __builtin_amdgcn_exp2f(q2[0] * lo_bf(t[i].x)); z[0] += p; wa[0] += p * lo_bf(t[i].z);
            p = __builtin_amdgcn_exp2f(q2[1] * hi_bf(t[i].x)); z[1] += p; wa[1] += p * hi_bf(t[i].z);
            p = __builtin_amdgcn_exp2f(q2[2] * lo_bf(t[i].y)); z[2] += p; wa[2] += p * lo_bf(t[i].w);
            p = __builtin_amdgcn_exp2f(q2[3] * hi_bf(t[i].y)); z[3] += p; wa[3] += p * hi_bf(t[i].w);
        }
    }

    float msg[4];
#pragma unroll
    for (int j = 0; j < 4; ++j) msg[j] = wa[j] * frcp(z[j] + 1e-6f);

    node_tail(hh, msg, Wo + l * 16, bo + l * 4, ln1_g + l * 4, ln1_b + l * 4,
              W1 + l * 32, b1 + l * 8, W2 + l * 32, b2 + l * 4,
              ln2_g + l * 4, ln2_b + l * 4);

    // h_{l+1}: full write for l<2; at l==2 only the agent rows are consumed downstream
    if (l < 2 || own == agent_nodes[b])
        hout[n] = make_float4(hh[0], hh[1], hh[2], hh[3]);

    // kv for layer l+1
    kvout[n] = kv_pack(hh, Wk + (l + 1) * 16, bk + (l + 1) * 4,
                        Wv + (l + 1) * 16, bv + (l + 1) * 4);
}

// ====== final GAT layer (l=3): only the 128 agent nodes matter ======
__global__ __launch_bounds__(64) void gat_final_kernel(
    const float4* __restrict__ h3, const uint4* __restrict__ kv3,
    const int* __restrict__ src, const int* __restrict__ agent_nodes,
    const float* __restrict__ Wq, const float* __restrict__ bq,
    const float* __restrict__ Wo, const float* __restrict__ bo,
    const float* __restrict__ ln1_g, const float* __restrict__ ln1_b,
    const float* __restrict__ W1, const float* __restrict__ b1,
    const float* __restrict__ W2, const float* __restrict__ b2,
    const float* __restrict__ ln2_g, const float* __restrict__ ln2_b,
    float* __restrict__ gat_out)
{
    const int b = blockIdx.x * 64 + threadIdx.x;
    if (b >= NB) return;
    const int l = NL - 1;
    const int ag = agent_nodes[b];

    float4 h4 = h3[(size_t)b * NN + ag];
    float hh[4] = {h4.x, h4.y, h4.z, h4.w};

    float q2[4];
    {
        const float* wq = Wq + l * 16; const float* bql = bq + l * 4;
#pragma unroll
        for (int j = 0; j < 4; ++j) {
            float sq = bql[j];
#pragma unroll
            for (int i = 0; i < 4; ++i) sq += hh[i] * wq[i * 4 + j];
            q2[j] = sq * LOG2E;
        }
    }

    const uint4* slab = kv3 + (size_t)b * NN;
    const int* sp = src + ag * DEG;
    float z[4] = {0.f, 0.f, 0.f, 0.f}, wa[4] = {0.f, 0.f, 0.f, 0.f};
#pragma unroll
    for (int e = 0; e < 16; ++e) {
        uint4 t = slab[sp[e]];
        float p;
        p = __builtin_amdgcn_exp2f(q2[0] * lo_bf(t.x)); z[0] += p; wa[0] += p * lo_bf(t.z);
        p = __builtin_amdgcn_exp2f(q2[1] * hi_bf(t.x)); z[1] += p; wa[1] += p * hi_bf(t.z);
        p = __builtin_amdgcn_exp2f(q2[2] * lo_bf(t.y)); z[2] += p; wa[2] += p * lo_bf(t.w);
        p = __builtin_amdgcn_exp2f(q2[3] * hi_bf(t.y)); z[3] += p; wa[3] += p * hi_bf(t.w);
    }
    float msg[4];
#pragma unroll
    for (int j = 0; j < 4; ++j) msg[j] = wa[j] * frcp(z[j] + 1e-6f);

    node_tail(hh, msg, Wo + l * 16, bo + l * 4, ln1_g + l * 4, ln1_b + l * 4,
              W1 + l * 32, b1 + l * 8, W2 + l * 32, b2 + l * 4,
              ln2_g + l * 4, ln2_b + l * 4);
#pragma unroll
    for (int j = 0; j < 4; ++j) gat_out[b * 4 + j] = hh[j];
}

// ===================== fallback: one block per graph =====================
__global__ __launch_bounds__(1024) void gat_single_kernel(
    const float* __restrict__ x, const int* __restrict__ src,
    const int* __restrict__ agent_nodes,
    const float* __restrict__ We, const float* __restrict__ be,
    const float* __restrict__ Wq, const float* __restrict__ bq,
    const float* __restrict__ Wk, const float* __restrict__ bk,
    const float* __restrict__ Wv, const float* __restrict__ bv,
    const float* __restrict__ Wo, const float* __restrict__ bo,
    const float* __restrict__ ln1_g, const float* __restrict__ ln1_b,
    const float* __restrict__ W1, const float* __restrict__ b1,
    const float* __restrict__ W2, const float* __restrict__ b2,
    const float* __restrict__ ln2_g, const float* __restrict__ ln2_b,
    float* __restrict__ gat_out)
{
    __shared__ uint4 kv[NN];
    const int b = blockIdx.x;
    const int tid = threadIdx.x;
    float h[2][4];
#pragma unroll
    for (int u = 0; u < 2; ++u) {
        const int n = tid + u * 1024;
        const float4* xr = reinterpret_cast<const float4*>(x + ((size_t)b * NN + n) * EMBD);
        float xv[16];
#pragma unroll
        for (int t4 = 0; t4 < 4; ++t4) {
            float4 t = xr[t4];
            xv[t4 * 4 + 0] = t.x; xv[t4 * 4 + 1] = t.y;
            xv[t4 * 4 + 2] = t.z; xv[t4 * 4 + 3] = t.w;
        }
#pragma unroll
        for (int j = 0; j < 4; ++j) {
            float s = be[j];
#pragma unroll
            for (int i = 0; i < 16; ++i) s += xv[i] * We[i * 4 + j];
            h[u][j] = s;
        }
    }
    for (int l = 0; l < NL; ++l) {
        float q2[2][4];
        const float* wq = Wq + l * 16; const float* bql = bq + l * 4;
        const float* wk = Wk + l * 16; const float* bkl = bk + l * 4;
        const float* wv = Wv + l * 16; const float* bvl = bv + l * 4;
#pragma unroll
        for (int u = 0; u < 2; ++u) {
            const int n = tid + u * 1024;
            float kk[4], vv[4];
#pragma unroll
            for (int j = 0; j < 4; ++j) {
                float sq = bql[j], sk = bkl[j], sv = bvl[j];
#pragma unroll
                for (int i = 0; i < 4; ++i) {
                    sq += h[u][i] * wq[i * 4 + j];
                    sk += h[u][i] * wk[i * 4 + j];
                    sv += h[u][i] * wv[i * 4 + j];
                }
                q2[u][j] = sq * LOG2E; kk[j] = sk; vv[j] = sv;
            }
            kv[n] = make_uint4(pk_bf16(kk[0], kk[1]), pk_bf16(kk[2], kk[3]),
                               pk_bf16(vv[0], vv[1]), pk_bf16(vv[2], vv[3]));
        }
        __syncthreads();
        const float* wo = Wo + l * 16; const float* bol = bo + l * 4;
        const float* g1 = ln1_g + l * 4; const float* be1 = ln1_b + l * 4;
        const float* w1 = W1 + l * 32;  const float* b1l = b1 + l * 8;
        const float* w2 = W2 + l * 32;  const float* b2l = b2 + l * 4;
        const float* g2 = ln2_g + l * 4; const float* be2 = ln2_b + l * 4;
#pragma unroll
        for (int u = 0; u < 2; ++u) {
            const int n = tid + u * 1024;
            const int4* sp = reinterpret_cast<const int4*>(src + n * DEG);
            float z[4] = {0.f,0.f,0.f,0.f}, wa[4] = {0.f,0.f,0.f,0.f};
#pragma unroll
            for (int eb = 0; eb < 4; ++eb) {
                int4 s4 = sp[eb];
                int sis[4] = {s4.x, s4.y, s4.z, s4.w};
#pragma unroll
                for (int e = 0; e < 4; ++e) {
                    const uint4 t = kv[sis[e]];
                    float p0 = __builtin_amdgcn_exp2f(q2[u][0] * lo_bf(t.x));
                    float p1 = __builtin_amdgcn_exp2f(q2[u][1] * hi_bf(t.x));
                    float p2 = __builtin_amdgcn_exp2f(q2[u][2] * lo_bf(t.y));
                    float p3 = __builtin_amdgcn_exp2f(q2[u][3] * hi_bf(t.y));
                    z[0] += p0; z[1] += p1; z[2] += p2; z[3] += p3;
                    wa[0] += p0 * lo_bf(t.z); wa[1] += p1 * hi_bf(t.z);
                    wa[2] += p2 * lo_bf(t.w); wa[3] += p3 * hi_bf(t.w);
                }
            }
            float msg[4];
#pragma unroll
            for (int j = 0; j < 4; ++j) msg[j] = wa[j] * frcp(z[j] + 1e-6f);
            node_tail(h[u], msg, wo, bol, g1, be1, w1, b1l, w2, b2l, g2, be2);
        }
        __syncthreads();
    }
    const int agent = agent_nodes[b];
#pragma unroll
    for (int u = 0; u < 2; ++u) {
        if (tid + u * 1024 == agent) {
#pragma unroll
            for (int j = 0; j < 4; ++j) gat_out[b * 4 + j] = h[u][j];
        }
    }
}

// --- MLP stage 1: split-K partial dot products for fc1 ---
__global__ __launch_bounds__(256) void mlp1_kernel(
    const float* __restrict__ obs, const float* __restrict__ gat,
    const float* __restrict__ oW1, float* __restrict__ partial)
{
    __shared__ float red[4][HID];
    const int blk = blockIdx.x;
    const int b = blk >> 4;
    const int ks = blk & (KS - 1);
    const int tid = threadIdx.x;
    const int w = tid >> 6, lane = tid & 63;
    const float* ob = obs + (size_t)b * OBSD;

    const int c0 = ks * CH;
    const int c1 = min(c0 + CH, OBSD);
    const int wl = (c1 - c0 + 3) >> 2;
    const int s0 = c0 + w * wl;
    const int s1 = min(s0 + wl, c1);

    if (lane < HID) {
        float a0 = 0.f, a1 = 0.f, a2 = 0.f, a3 = 0.f;
        int i = s0;
        for (; i + 4 <= s1; i += 4) {
            a0 += ob[i + 0] * oW1[(size_t)(i + 4) * HID + lane];
            a1 += ob[i + 1] * oW1[(size_t)(i + 5) * HID + lane];
            a2 += ob[i + 2] * oW1[(size_t)(i + 6) * HID + lane];
            a3 += ob[i + 3] * oW1[(size_t)(i + 7) * HID + lane];
        }
        for (; i < s1; ++i) a0 += ob[i] * oW1[(size_t)(i + 4) * HID + lane];
        if (ks == 0 && w == 0) {
#pragma unroll
            for (int k = 0; k < 4; ++k) a1 += gat[b * 4 + k] * oW1[k * HID + lane];
        }
        red[w][lane] = a0 + a1 + a2 + a3;
    }
    __syncthreads();
    if (tid < HID) {
        partial[(size_t)blk * HID + tid] =
            red[0][tid] + red[1][tid] + red[2][tid] + red[3][tid];
    }
}

// --- MLP stage 2: reduce partials, tanh, fc2, tanh, fc3 ---
__global__ __launch_bounds__(64) void mlp2_kernel(
    const float* __restrict__ partial,
    const float* __restrict__ ob1,
    const float* __restrict__ oW2, const float* __restrict__ ob2,
    const float* __restrict__ oW3, const float* __restrict__ ob3,
    float* __restrict__ out)
{
    __shared__ float hm1[HID], hm2[HID];
    const int b = blockIdx.x;
    const int tid = threadIdx.x;
    if (tid < HID) {
        float s = ob1[tid];
        const float* p = partial + (size_t)b * KS * HID;
#pragma unroll
        for (int ks = 0; ks < KS; ++ks) s += p[ks * HID + tid];
        hm1[tid] = tanhf(s);
    }
    __syncthreads();
    if (tid < HID) {
        float s = ob2[tid];
        for (int k = 0; k < HID; ++k) s += hm1[k] * oW2[k * HID + tid];
        hm2[tid] = tanhf(s);
    }
    __syncthreads();
    if (tid < NOUT) {
        float s = ob3[tid];
        for (int k = 0; k < HID; ++k) s += hm2[k] * oW3[k * NOUT + tid];
        out[(size_t)b * NOUT + tid] = s;
    }
}

extern "C" void kernel_launch(void* const* d_in, const int* in_sizes, int n_in,
                              void* d_out, int out_size, void* d_ws, size_t ws_size,
                              hipStream_t stream) {
    const float* x      = (const float*)d_in[0];
    const float* obs    = (const float*)d_in[1];
    const int*   src    = (const int*)d_in[2];
    /* d_in[3] = dst: structurally repeat(arange(N), DEG) — not needed */
    const int*   agent  = (const int*)d_in[4];
    const float* We     = (const float*)d_in[5];
    const float* be     = (const float*)d_in[6];
    const float* Wq     = (const float*)d_in[7];
    const float* bq     = (const float*)d_in[8];
    const float* Wk     = (const float*)d_in[9];
    const float* bk     = (const float*)d_in[10];
    const float* Wv     = (const float*)d_in[11];
    const float* bv     = (const float*)d_in[12];
    const float* Wo     = (const float*)d_in[13];
    const float* bo     = (const float*)d_in[14];
    const float* ln1_g  = (const float*)d_in[15];
    const float* ln1_b  = (const float*)d_in[16];
    const float* W1     = (const float*)d_in[17];
    const float* b1     = (const float*)d_in[18];
    const float* W2     = (const float*)d_in[19];
    const float* b2     = (const float*)d_in[20];
    const float* ln2_g  = (const float*)d_in[21];
    const float* ln2_b  = (const float*)d_in[22];
    const float* oW1    = (const float*)d_in[23];
    const float* ob1    = (const float*)d_in[24];
    const float* oW2    = (const float*)d_in[25];
    const float* ob2    = (const float*)d_in[26];
    const float* oW3    = (const float*)d_in[27];
    const float* ob3    = (const float*)d_in[28];

    float* out = (float*)d_out;
    char*  ws  = (char*)d_ws;

    const size_t hbytes = (size_t)NB * NN * 16;          // 4 MiB
    const size_t need   = 4 * hbytes + 2048 + 368640;

    if (ws_size >= need) {
        float4* hA      = (float4*)ws;
        float4* hB      = (float4*)(ws + hbytes);
        uint4*  kvA     = (uint4*)(ws + 2 * hbytes);
        uint4*  kvB     = (uint4*)(ws + 3 * hbytes);
        float*  gat_out = (float*)(ws + 4 * hbytes);
        float*  partial = (float*)(ws + 4 * hbytes + 2048);

        embed_proj_kernel<<<NB * NN / 256, 256, 0, stream>>>(x, We, be, Wk, bk, Wv, bv, hA, kvA);

        float4* hi = hA; float4* ho = hB;
        uint4*  ki = kvA; uint4* ko = kvB;
        for (int l = 0; l < NL - 1; ++l) {
            gat_layer_kernel<<<NB * NN / 256, 256, 0, stream>>>(hi, ki, ho, ko, src, agent, l,
                Wq, bq, Wk, bk, Wv, bv, Wo, bo, ln1_g, ln1_b, W1, b1, W2, b2, ln2_g, ln2_b);
            float4* th = hi; hi = ho; ho = th;
            uint4*  tk = ki; ki = ko; ko = tk;
        }
        // hi = h3 (agent rows valid), ki = kv3
        gat_final_kernel<<<(NB + 63) / 64, 64, 0, stream>>>(hi, ki, src, agent,
            Wq, bq, Wo, bo, ln1_g, ln1_b, W1, b1, W2, b2, ln2_g, ln2_b, gat_out);

        mlp1_kernel<<<NB * KS, 256, 0, stream>>>(obs, gat_out, oW1, partial);
        mlp2_kernel<<<NB, 64, 0, stream>>>(partial, ob1, oW2, ob2, oW3, ob3, out);
    } else {
        float* gat_out = (float*)ws;
        float* partial = (float*)(ws + 2048);
        gat_single_kernel<<<NB, 1024, 0, stream>>>(x, src, agent, We, be, Wq, bq, Wk, bk,
                                                   Wv, bv, Wo, bo, ln1_g, ln1_b, W1, b1,
                                                   W2, b2, ln2_g, ln2_b, gat_out);
        mlp1_kernel<<<NB * KS, 256, 0, stream>>>(obs, gat_out, oW1, partial);
        mlp2_kernel<<<NB, 64, 0, stream>>>(partial, ob1, oW2, ob2, oW3, ob3, out);
    }
}

// Round 7
// 68.678 us; speedup vs baseline: 1.1046x; 1.1046x over previous
//
#include <hip/hip_runtime.h>
#include <hip/hip_bf16.h>

#define NB 128
#define NN 2048
#define DEG 16
#define EMBD 16
#define NL 4
#define OBSD 6154
#define HID 45
#define NOUT 15
#define KS 16
#define CH 385   // ceil(OBSD / KS)
#define LOG2E 1.44269504f

__device__ __forceinline__ float frcp(float v) { return __builtin_amdgcn_rcpf(v); }

__device__ __forceinline__ uint32_t pk_bf16(float a, float b) {
    uint32_t ua = __float_as_uint(a); ua += 0x7fffu + ((ua >> 16) & 1u);
    uint32_t ub = __float_as_uint(b); ub += 0x7fffu + ((ub >> 16) & 1u);
    return (ua >> 16) | (ub & 0xffff0000u);
}
__device__ __forceinline__ float lo_bf(uint32_t u) { return __uint_as_float(u << 16); }
__device__ __forceinline__ float hi_bf(uint32_t u) { return __uint_as_float(u & 0xffff0000u); }

__device__ __forceinline__ void ln4(const float* p, const float* g, const float* bb, float* o) {
    float m = 0.25f * (p[0] + p[1] + p[2] + p[3]);
    float var = 0.f;
#pragma unroll
    for (int j = 0; j < 4; ++j) { float d = p[j] - m; var += d * d; }
    var *= 0.25f;
    float rs = rsqrtf(var + 1e-5f);
#pragma unroll
    for (int j = 0; j < 4; ++j) o[j] = g[j] * (p[j] - m) * rs + bb[j];
}

// residual tail after attention message: Wo + LN1 + FFN + LN2 (updates hh in place)
__device__ __forceinline__ void node_tail(float* hh, const float* msg,
    const float* wo, const float* bol, const float* g1, const float* be1,
    const float* w1, const float* b1l, const float* w2, const float* b2l,
    const float* g2, const float* be2)
{
    float pre[4];
#pragma unroll
    for (int j = 0; j < 4; ++j) {
        float s = bol[j];
#pragma unroll
        for (int i = 0; i < 4; ++i) s += msg[i] * wo[i * 4 + j];
        pre[j] = hh[j] + s;
    }
    float hn[4];
    ln4(pre, g1, be1, hn);
    float mid[8];
#pragma unroll
    for (int j = 0; j < 8; ++j) {
        float s = b1l[j];
#pragma unroll
        for (int i = 0; i < 4; ++i) s += hn[i] * w1[i * 8 + j];
        mid[j] = fmaxf(s, 0.f);
    }
    float pre2[4];
#pragma unroll
    for (int j = 0; j < 4; ++j) {
        float s = b2l[j];
#pragma unroll
        for (int i = 0; i < 8; ++i) s += mid[i] * w2[i * 4 + j];
        pre2[j] = hn[j] + s;
    }
    ln4(pre2, g2, be2, hh);
}

// ============ K0: GAT layer 0 (blocks 0..255) + mlp1-obs (blocks 256..383) ============
__global__ __launch_bounds__(1024) void gat0_mlp_kernel(
    const float* __restrict__ x, float4* __restrict__ hout,
    const int* __restrict__ src,
    const float* __restrict__ We, const float* __restrict__ be,
    const float* __restrict__ Wq, const float* __restrict__ bq,
    const float* __restrict__ Wk, const float* __restrict__ bk,
    const float* __restrict__ Wv, const float* __restrict__ bv,
    const float* __restrict__ Wo, const float* __restrict__ bo,
    const float* __restrict__ ln1_g, const float* __restrict__ ln1_b,
    const float* __restrict__ W1, const float* __restrict__ b1,
    const float* __restrict__ W2, const float* __restrict__ b2,
    const float* __restrict__ ln2_g, const float* __restrict__ ln2_b,
    const float* __restrict__ obs, const float* __restrict__ oW1,
    float* __restrict__ fc1obs)
{
    __shared__ uint4 kv[NN];   // GAT: packed kv.  MLP blocks reuse as float red[16][64].
    const int bid = blockIdx.x;
    const int tid = threadIdx.x;

    if (bid >= 2 * NB) {
        // ---------------- mlp1: obs-part of fc1 for batch row b ----------------
        float* red = reinterpret_cast<float*>(kv);   // [16][64]
        const int b = bid - 2 * NB;
        const int w = tid >> 6, lane = tid & 63;
        const float* ob = obs + (size_t)b * OBSD;
        const int s0 = w * CH;
        const int s1 = min(s0 + CH, OBSD);
        float a0 = 0.f, a1 = 0.f, a2 = 0.f, a3 = 0.f;
        if (lane < HID) {
            int i = s0;
            for (; i + 4 <= s1; i += 4) {
                a0 += ob[i + 0] * oW1[(size_t)(i + 4) * HID + lane];
                a1 += ob[i + 1] * oW1[(size_t)(i + 5) * HID + lane];
                a2 += ob[i + 2] * oW1[(size_t)(i + 6) * HID + lane];
                a3 += ob[i + 3] * oW1[(size_t)(i + 7) * HID + lane];
            }
            for (; i < s1; ++i) a0 += ob[i] * oW1[(size_t)(i + 4) * HID + lane];
        }
        red[w * 64 + lane] = a0 + a1 + a2 + a3;
        __syncthreads();
        if (tid < HID) {
            float s = 0.f;
#pragma unroll
            for (int ww = 0; ww < 16; ++ww) s += red[ww * 64 + tid];
            fc1obs[b * HID + tid] = s;
        }
        return;
    }

    // ---------------- GAT layer 0 (embed fused) ----------------
    const int b = bid >> 1, half = bid & 1;
    const int own = half * 1024 + tid;
    const int l = 0;

    int su[16];
    {
        const int4* sp = reinterpret_cast<const int4*>(src + own * DEG);
#pragma unroll
        for (int t4 = 0; t4 < 4; ++t4) {
            int4 s4 = sp[t4];
            su[t4 * 4 + 0] = s4.x; su[t4 * 4 + 1] = s4.y;
            su[t4 * 4 + 2] = s4.z; su[t4 * 4 + 3] = s4.w;
        }
    }

    float hv[2][4];
#pragma unroll
    for (int c = 0; c < 2; ++c) {
        const float4* xr = reinterpret_cast<const float4*>(
            x + ((size_t)b * NN + c * 1024 + tid) * EMBD);
        float xv[16];
#pragma unroll
        for (int t4 = 0; t4 < 4; ++t4) {
            float4 t = xr[t4];
            xv[t4 * 4 + 0] = t.x; xv[t4 * 4 + 1] = t.y;
            xv[t4 * 4 + 2] = t.z; xv[t4 * 4 + 3] = t.w;
        }
#pragma unroll
        for (int j = 0; j < 4; ++j) {
            float s = be[j];
#pragma unroll
            for (int i = 0; i < 16; ++i) s += xv[i] * We[i * 4 + j];
            hv[c][j] = s;
        }
    }

    const float* wk = Wk + l * 16; const float* bkl = bk + l * 4;
    const float* wv = Wv + l * 16; const float* bvl = bv + l * 4;
#pragma unroll
    for (int c = 0; c < 2; ++c) {
        float kk[4], vv[4];
#pragma unroll
        for (int j = 0; j < 4; ++j) {
            float sk = bkl[j], sv = bvl[j];
#pragma unroll
            for (int i = 0; i < 4; ++i) {
                sk += hv[c][i] * wk[i * 4 + j];
                sv += hv[c][i] * wv[i * 4 + j];
            }
            kk[j] = sk; vv[j] = sv;
        }
        kv[c * 1024 + tid] = make_uint4(pk_bf16(kk[0], kk[1]), pk_bf16(kk[2], kk[3]),
                                        pk_bf16(vv[0], vv[1]), pk_bf16(vv[2], vv[3]));
    }

    float hh[4] = {hv[half][0], hv[half][1], hv[half][2], hv[half][3]};
    float q2[4];
    {
        const float* wq = Wq + l * 16; const float* bql = bq + l * 4;
#pragma unroll
        for (int j = 0; j < 4; ++j) {
            float sq = bql[j];
#pragma unroll
            for (int i = 0; i < 4; ++i) sq += hh[i] * wq[i * 4 + j];
            q2[j] = sq * LOG2E;
        }
    }
    __syncthreads();

    float z[4] = {0.f, 0.f, 0.f, 0.f}, wa[4] = {0.f, 0.f, 0.f, 0.f};
#pragma unroll
    for (int eb = 0; eb < 4; ++eb) {
        uint4 t0 = kv[su[eb * 4 + 0]];
        uint4 t1 = kv[su[eb * 4 + 1]];
        uint4 t2 = kv[su[eb * 4 + 2]];
        uint4 t3 = kv[su[eb * 4 + 3]];
        float p;
        p = __builtin_amdgcn_exp2f(q2[0] * lo_bf(t0.x)); z[0] += p; wa[0] += p * lo_bf(t0.z);
        p = __builtin_amdgcn_exp2f(q2[1] * hi_bf(t0.x)); z[1] += p; wa[1] += p * hi_bf(t0.z);
        p = __builtin_amdgcn_exp2f(q2[2] * lo_bf(t0.y)); z[2] += p; wa[2] += p * lo_bf(t0.w);
        p = __builtin_amdgcn_exp2f(q2[3] * hi_bf(t0.y)); z[3] += p; wa[3] += p * hi_bf(t0.w);
        p = __builtin_amdgcn_exp2f(q2[0] * lo_bf(t1.x)); z[0] += p; wa[0] += p * lo_bf(t1.z);
        p = __builtin_amdgcn_exp2f(q2[1] * hi_bf(t1.x)); z[1] += p; wa[1] += p * hi_bf(t1.z);
        p = __builtin_amdgcn_exp2f(q2[2] * lo_bf(t1.y)); z[2] += p; wa[2] += p * lo_bf(t1.w);
        p = __builtin_amdgcn_exp2f(q2[3] * hi_bf(t1.y)); z[3] += p; wa[3] += p * hi_bf(t1.w);
        p = __builtin_amdgcn_exp2f(q2[0] * lo_bf(t2.x)); z[0] += p; wa[0] += p * lo_bf(t2.z);
        p = __builtin_amdgcn_exp2f(q2[1] * hi_bf(t2.x)); z[1] += p; wa[1] += p * hi_bf(t2.z);
        p = __builtin_amdgcn_exp2f(q2[2] * lo_bf(t2.y)); z[2] += p; wa[2] += p * lo_bf(t2.w);
        p = __builtin_amdgcn_exp2f(q2[3] * hi_bf(t2.y)); z[3] += p; wa[3] += p * hi_bf(t2.w);
        p = __builtin_amdgcn_exp2f(q2[0] * lo_bf(t3.x)); z[0] += p; wa[0] += p * lo_bf(t3.z);
        p = __builtin_amdgcn_exp2f(q2[1] * hi_bf(t3.x)); z[1] += p; wa[1] += p * hi_bf(t3.z);
        p = __builtin_amdgcn_exp2f(q2[2] * lo_bf(t3.y)); z[2] += p; wa[2] += p * lo_bf(t3.w);
        p = __builtin_amdgcn_exp2f(q2[3] * hi_bf(t3.y)); z[3] += p; wa[3] += p * hi_bf(t3.w);
    }

    float msg[4];
#pragma unroll
    for (int j = 0; j < 4; ++j) msg[j] = wa[j] * frcp(z[j] + 1e-6f);

    node_tail(hh, msg, Wo + l * 16, bo + l * 4, ln1_g + l * 4, ln1_b + l * 4,
              W1 + l * 32, b1 + l * 8, W2 + l * 32, b2 + l * 4,
              ln2_g + l * 4, ln2_b + l * 4);

    hout[(size_t)b * NN + own] = make_float4(hh[0], hh[1], hh[2], hh[3]);
}

// ============ K1/K2: GAT layer l (l = 1, 2), 2 blocks/graph ============
__global__ __launch_bounds__(1024) void gat_layer_kernel(
    const float4* __restrict__ hin, float4* __restrict__ hout,
    const int* __restrict__ src, const int l,
    const float* __restrict__ Wq, const float* __restrict__ bq,
    const float* __restrict__ Wk, const float* __restrict__ bk,
    const float* __restrict__ Wv, const float* __restrict__ bv,
    const float* __restrict__ Wo, const float* __restrict__ bo,
    const float* __restrict__ ln1_g, const float* __restrict__ ln1_b,
    const float* __restrict__ W1, const float* __restrict__ b1,
    const float* __restrict__ W2, const float* __restrict__ b2,
    const float* __restrict__ ln2_g, const float* __restrict__ ln2_b)
{
    __shared__ uint4 kv[NN];
    const int bid = blockIdx.x;
    const int b = bid >> 1, half = bid & 1;
    const int tid = threadIdx.x;
    const int own = half * 1024 + tid;

    int su[16];
    {
        const int4* sp = reinterpret_cast<const int4*>(src + own * DEG);
#pragma unroll
        for (int t4 = 0; t4 < 4; ++t4) {
            int4 s4 = sp[t4];
            su[t4 * 4 + 0] = s4.x; su[t4 * 4 + 1] = s4.y;
            su[t4 * 4 + 2] = s4.z; su[t4 * 4 + 3] = s4.w;
        }
    }

    const float4* hb = hin + (size_t)b * NN;
    float hv[2][4];
    {
        float4 a0 = hb[tid];
        float4 a1 = hb[1024 + tid];
        hv[0][0] = a0.x; hv[0][1] = a0.y; hv[0][2] = a0.z; hv[0][3] = a0.w;
        hv[1][0] = a1.x; hv[1][1] = a1.y; hv[1][2] = a1.z; hv[1][3] = a1.w;
    }

    const float* wk = Wk + l * 16; const float* bkl = bk + l * 4;
    const float* wv = Wv + l * 16; const float* bvl = bv + l * 4;
#pragma unroll
    for (int c = 0; c < 2; ++c) {
        float kk[4], vv[4];
#pragma unroll
        for (int j = 0; j < 4; ++j) {
            float sk = bkl[j], sv = bvl[j];
#pragma unroll
            for (int i = 0; i < 4; ++i) {
                sk += hv[c][i] * wk[i * 4 + j];
                sv += hv[c][i] * wv[i * 4 + j];
            }
            kk[j] = sk; vv[j] = sv;
        }
        kv[c * 1024 + tid] = make_uint4(pk_bf16(kk[0], kk[1]), pk_bf16(kk[2], kk[3]),
                                        pk_bf16(vv[0], vv[1]), pk_bf16(vv[2], vv[3]));
    }

    float hh[4] = {hv[half][0], hv[half][1], hv[half][2], hv[half][3]};
    float q2[4];
    {
        const float* wq = Wq + l * 16; const float* bql = bq + l * 4;
#pragma unroll
        for (int j = 0; j < 4; ++j) {
            float sq = bql[j];
#pragma unroll
            for (int i = 0; i < 4; ++i) sq += hh[i] * wq[i * 4 + j];
            q2[j] = sq * LOG2E;
        }
    }
    __syncthreads();

    float z[4] = {0.f, 0.f, 0.f, 0.f}, wa[4] = {0.f, 0.f, 0.f, 0.f};
#pragma unroll
    for (int eb = 0; eb < 4; ++eb) {
        uint4 t0 = kv[su[eb * 4 + 0]];
        uint4 t1 = kv[su[eb * 4 + 1]];
        uint4 t2 = kv[su[eb * 4 + 2]];
        uint4 t3 = kv[su[eb * 4 + 3]];
        float p;
        p = __builtin_amdgcn_exp2f(q2[0] * lo_bf(t0.x)); z[0] += p; wa[0] += p * lo_bf(t0.z);
        p = __builtin_amdgcn_exp2f(q2[1] * hi_bf(t0.x)); z[1] += p; wa[1] += p * hi_bf(t0.z);
        p = __builtin_amdgcn_exp2f(q2[2] * lo_bf(t0.y)); z[2] += p; wa[2] += p * lo_bf(t0.w);
        p = __builtin_amdgcn_exp2f(q2[3] * hi_bf(t0.y)); z[3] += p; wa[3] += p * hi_bf(t0.w);
        p = __builtin_amdgcn_exp2f(q2[0] * lo_bf(t1.x)); z[0] += p; wa[0] += p * lo_bf(t1.z);
        p = __builtin_amdgcn_exp2f(q2[1] * hi_bf(t1.x)); z[1] += p; wa[1] += p * hi_bf(t1.z);
        p = __builtin_amdgcn_exp2f(q2[2] * lo_bf(t1.y)); z[2] += p; wa[2] += p * lo_bf(t1.w);
        p = __builtin_amdgcn_exp2f(q2[3] * hi_bf(t1.y)); z[3] += p; wa[3] += p * hi_bf(t1.w);
        p = __builtin_amdgcn_exp2f(q2[0] * lo_bf(t2.x)); z[0] += p; wa[0] += p * lo_bf(t2.z);
        p = __builtin_amdgcn_exp2f(q2[1] * hi_bf(t2.x)); z[1] += p; wa[1] += p * hi_bf(t2.z);
        p = __builtin_amdgcn_exp2f(q2[2] * lo_bf(t2.y)); z[2] += p; wa[2] += p * lo_bf(t2.w);
        p = __builtin_amdgcn_exp2f(q2[3] * hi_bf(t2.y)); z[3] += p; wa[3] += p * hi_bf(t2.w);
        p = __builtin_amdgcn_exp2f(q2[0] * lo_bf(t3.x)); z[0] += p; wa[0] += p * lo_bf(t3.z);
        p = __builtin_amdgcn_exp2f(q2[1] * hi_bf(t3.x)); z[1] += p; wa[1] += p * hi_bf(t3.z);
        p = __builtin_amdgcn_exp2f(q2[2] * lo_bf(t3.y)); z[2] += p; wa[2] += p * lo_bf(t3.w);
        p = __builtin_amdgcn_exp2f(q2[3] * hi_bf(t3.y)); z[3] += p; wa[3] += p * hi_bf(t3.w);
    }

    float msg[4];
#pragma unroll
    for (int j = 0; j < 4; ++j) msg[j] = wa[j] * frcp(z[j] + 1e-6f);

    node_tail(hh, msg, Wo + l * 16, bo + l * 4, ln1_g + l * 4, ln1_b + l * 4,
              W1 + l * 32, b1 + l * 8, W2 + l * 32, b2 + l * 4,
              ln2_g + l * 4, ln2_b + l * 4);

    hout[(size_t)b * NN + own] = make_float4(hh[0], hh[1], hh[2], hh[3]);
}

// ===== K3: final GAT layer at agent nodes + MLP head. 1 wave per batch row =====
__global__ __launch_bounds__(64) void final_kernel(
    const float4* __restrict__ h3, const int* __restrict__ src,
    const int* __restrict__ agent_nodes,
    const float* __restrict__ Wq, const float* __restrict__ bq,
    const float* __restrict__ Wk, const float* __restrict__ bk,
    const float* __restrict__ Wv, const float* __restrict__ bv,
    const float* __restrict__ Wo, const float* __restrict__ bo,
    const float* __restrict__ ln1_g, const float* __restrict__ ln1_b,
    const float* __restrict__ W1, const float* __restrict__ b1,
    const float* __restrict__ W2, const float* __restrict__ b2,
    const float* __restrict__ ln2_g, const float* __restrict__ ln2_b,
    const float* __restrict__ fc1obs, const float* __restrict__ oW1,
    const float* __restrict__ ob1,
    const float* __restrict__ oW2, const float* __restrict__ ob2,
    const float* __restrict__ oW3, const float* __restrict__ ob3,
    float* __restrict__ out)
{
    __shared__ float hm1s[HID];
    __shared__ float hm2s[HID];
    const int b = blockIdx.x;
    const int lane = threadIdx.x;
    const int e = lane >> 2, hd = lane & 3;   // edge, head
    const int l = NL - 1;

    const int ag = agent_nodes[b];
    const float4 ha4 = h3[(size_t)b * NN + ag];
    const float ha[4] = {ha4.x, ha4.y, ha4.z, ha4.w};

    // per-lane q for its head
    float qh;
    {
        const float* wq = Wq + l * 16;
        qh = bq[l * 4 + hd];
#pragma unroll
        for (int i = 0; i < 4; ++i) qh += ha[i] * wq[i * 4 + hd];
        qh *= LOG2E;
    }

    // neighbor e: k,v for head hd projected in-register from h3
    const int ne = src[ag * DEG + e];
    const float4 hn4 = h3[(size_t)b * NN + ne];
    float kh, vh;
    {
        const float* wk = Wk + l * 16; const float* wv = Wv + l * 16;
        kh = bk[l * 4 + hd]; vh = bv[l * 4 + hd];
#pragma unroll
        for (int i = 0; i < 4; ++i) {
            const float hni = (i == 0) ? hn4.x : (i == 1) ? hn4.y : (i == 2) ? hn4.z : hn4.w;
            kh += hni * wk[i * 4 + hd];
            vh += hni * wv[i * 4 + hd];
        }
    }

    float p = __builtin_amdgcn_exp2f(qh * kh);
    float z = p, wv_s = p * vh;
    // butterfly over edge bits (lanes differing in bits 2..5 share the same head)
#pragma unroll
    for (int m = 4; m <= 32; m <<= 1) {
        z    += __shfl_xor(z, m, 64);
        wv_s += __shfl_xor(wv_s, m, 64);
    }
    float msg_h = wv_s * frcp(z + 1e-6f);

    // quad-gather all 4 heads' msg
    float msg[4];
#pragma unroll
    for (int j = 0; j < 4; ++j) msg[j] = __shfl(msg_h, (lane & ~3) + j, 64);

    float hh[4] = {ha[0], ha[1], ha[2], ha[3]};
    node_tail(hh, msg, Wo + l * 16, bo + l * 4, ln1_g + l * 4, ln1_b + l * 4,
              W1 + l * 32, b1 + l * 8, W2 + l * 32, b2 + l * 4,
              ln2_g + l * 4, ln2_b + l * 4);

    // MLP head: fc1 (obs part precomputed) -> tanh -> fc2 -> tanh -> fc3
    if (lane < HID) {
        float s = fc1obs[b * HID + lane] + ob1[lane];
#pragma unroll
        for (int k = 0; k < 4; ++k) s += hh[k] * oW1[k * HID + lane];
        hm1s[lane] = tanhf(s);
    }
    __syncthreads();
    if (lane < HID) {
        float s = ob2[lane];
        for (int k = 0; k < HID; ++k) s += hm1s[k] * oW2[k * HID + lane];
        hm2s[lane] = tanhf(s);
    }
    __syncthreads();
    if (lane < NOUT) {
        float s = ob3[lane];
        for (int k = 0; k < HID; ++k) s += hm2s[k] * oW3[k * NOUT + lane];
        out[(size_t)b * NOUT + lane] = s;
    }
}

// ===================== fallback: one block per graph + split-K mlp =====================
__global__ __launch_bounds__(1024) void gat_single_kernel(
    const float* __restrict__ x, const int* __restrict__ src,
    const int* __restrict__ agent_nodes,
    const float* __restrict__ We, const float* __restrict__ be,
    const float* __restrict__ Wq, const float* __restrict__ bq,
    const float* __restrict__ Wk, const float* __restrict__ bk,
    const float* __restrict__ Wv, const float* __restrict__ bv,
    const float* __restrict__ Wo, const float* __restrict__ bo,
    const float* __restrict__ ln1_g, const float* __restrict__ ln1_b,
    const float* __restrict__ W1, const float* __restrict__ b1,
    const float* __restrict__ W2, const float* __restrict__ b2,
    const float* __restrict__ ln2_g, const float* __restrict__ ln2_b,
    float* __restrict__ gat_out)
{
    __shared__ uint4 kv[NN];
    const int b = blockIdx.x;
    const int tid = threadIdx.x;
    float h[2][4];
#pragma unroll
    for (int u = 0; u < 2; ++u) {
        const int n = tid + u * 1024;
        const float4* xr = reinterpret_cast<const float4*>(x + ((size_t)b * NN + n) * EMBD);
        float xv[16];
#pragma unroll
        for (int t4 = 0; t4 < 4; ++t4) {
            float4 t = xr[t4];
            xv[t4 * 4 + 0] = t.x; xv[t4 * 4 + 1] = t.y;
            xv[t4 * 4 + 2] = t.z; xv[t4 * 4 + 3] = t.w;
        }
#pragma unroll
        for (int j = 0; j < 4; ++j) {
            float s = be[j];
#pragma unroll
            for (int i = 0; i < 16; ++i) s += xv[i] * We[i * 4 + j];
            h[u][j] = s;
        }
    }
    for (int l = 0; l < NL; ++l) {
        float q2[2][4];
        const float* wq = Wq + l * 16; const float* bql = bq + l * 4;
        const float* wk = Wk + l * 16; const float* bkl = bk + l * 4;
        const float* wv = Wv + l * 16; const float* bvl = bv + l * 4;
#pragma unroll
        for (int u = 0; u < 2; ++u) {
            const int n = tid + u * 1024;
            float kk[4], vv[4];
#pragma unroll
            for (int j = 0; j < 4; ++j) {
                float sq = bql[j], sk = bkl[j], sv = bvl[j];
#pragma unroll
                for (int i = 0; i < 4; ++i) {
                    sq += h[u][i] * wq[i * 4 + j];
                    sk += h[u][i] * wk[i * 4 + j];
                    sv += h[u][i] * wv[i * 4 + j];
                }
                q2[u][j] = sq * LOG2E; kk[j] = sk; vv[j] = sv;
            }
            kv[n] = make_uint4(pk_bf16(kk[0], kk[1]), pk_bf16(kk[2], kk[3]),
                               pk_bf16(vv[0], vv[1]), pk_bf16(vv[2], vv[3]));
        }
        __syncthreads();
        const float* wo = Wo + l * 16; const float* bol = bo + l * 4;
        const float* g1 = ln1_g + l * 4; const float* be1 = ln1_b + l * 4;
        const float* w1 = W1 + l * 32;  const float* b1l = b1 + l * 8;
        const float* w2 = W2 + l * 32;  const float* b2l = b2 + l * 4;
        const float* g2 = ln2_g + l * 4; const float* be2 = ln2_b + l * 4;
#pragma unroll
        for (int u = 0; u < 2; ++u) {
            const int n = tid + u * 1024;
            const int4* sp = reinterpret_cast<const int4*>(src + n * DEG);
            float z[4] = {0.f,0.f,0.f,0.f}, wa[4] = {0.f,0.f,0.f,0.f};
#pragma unroll
            for (int eb = 0; eb < 4; ++eb) {
                int4 s4 = sp[eb];
                int sis[4] = {s4.x, s4.y, s4.z, s4.w};
#pragma unroll
                for (int e = 0; e < 4; ++e) {
                    const uint4 t = kv[sis[e]];
                    float p0 = __builtin_amdgcn_exp2f(q2[u][0] * lo_bf(t.x));
                    float p1 = __builtin_amdgcn_exp2f(q2[u][1] * hi_bf(t.x));
                    float p2 = __builtin_amdgcn_exp2f(q2[u][2] * lo_bf(t.y));
                    float p3 = __builtin_amdgcn_exp2f(q2[u][3] * hi_bf(t.y));
                    z[0] += p0; z[1] += p1; z[2] += p2; z[3] += p3;
                    wa[0] += p0 * lo_bf(t.z); wa[1] += p1 * hi_bf(t.z);
                    wa[2] += p2 * lo_bf(t.w); wa[3] += p3 * hi_bf(t.w);
                }
            }
            float msg[4];
#pragma unroll
            for (int j = 0; j < 4; ++j) msg[j] = wa[j] * frcp(z[j] + 1e-6f);
            node_tail(h[u], msg, wo, bol, g1, be1, w1, b1l, w2, b2l, g2, be2);
        }
        __syncthreads();
    }
    const int agent = agent_nodes[b];
#pragma unroll
    for (int u = 0; u < 2; ++u) {
        if (tid + u * 1024 == agent) {
#pragma unroll
            for (int j = 0; j < 4; ++j) gat_out[b * 4 + j] = h[u][j];
        }
    }
}

__global__ __launch_bounds__(256) void mlp1_kernel(
    const float* __restrict__ obs, const float* __restrict__ gat,
    const float* __restrict__ oW1, float* __restrict__ partial)
{
    __shared__ float red[4][HID];
    const int blk = blockIdx.x;
    const int b = blk >> 4;
    const int ks = blk & (KS - 1);
    const int tid = threadIdx.x;
    const int w = tid >> 6, lane = tid & 63;
    const float* ob = obs + (size_t)b * OBSD;
    const int c0 = ks * CH;
    const int c1 = min(c0 + CH, OBSD);
    const int wl = (c1 - c0 + 3) >> 2;
    const int s0 = c0 + w * wl;
    const int s1 = min(s0 + wl, c1);
    if (lane < HID) {
        float a0 = 0.f, a1 = 0.f, a2 = 0.f, a3 = 0.f;
        int i = s0;
        for (; i + 4 <= s1; i += 4) {
            a0 += ob[i + 0] * oW1[(size_t)(i + 4) * HID + lane];
            a1 += ob[i + 1] * oW1[(size_t)(i + 5) * HID + lane];
            a2 += ob[i + 2] * oW1[(size_t)(i + 6) * HID + lane];
            a3 += ob[i + 3] * oW1[(size_t)(i + 7) * HID + lane];
        }
        for (; i < s1; ++i) a0 += ob[i] * oW1[(size_t)(i + 4) * HID + lane];
        if (ks == 0 && w == 0) {
#pragma unroll
            for (int k = 0; k < 4; ++k) a1 += gat[b * 4 + k] * oW1[k * HID + lane];
        }
        red[w][lane] = a0 + a1 + a2 + a3;
    }
    __syncthreads();
    if (tid < HID) {
        partial[(size_t)blk * HID + tid] =
            red[0][tid] + red[1][tid] + red[2][tid] + red[3][tid];
    }
}

__global__ __launch_bounds__(64) void mlp2_kernel(
    const float* __restrict__ partial, const float* __restrict__ ob1,
    const float* __restrict__ oW2, const float* __restrict__ ob2,
    const float* __restrict__ oW3, const float* __restrict__ ob3,
    float* __restrict__ out)
{
    __shared__ float hm1[HID], hm2[HID];
    const int b = blockIdx.x;
    const int tid = threadIdx.x;
    if (tid < HID) {
        float s = ob1[tid];
        const float* p = partial + (size_t)b * KS * HID;
#pragma unroll
        for (int ks = 0; ks < KS; ++ks) s += p[ks * HID + tid];
        hm1[tid] = tanhf(s);
    }
    __syncthreads();
    if (tid < HID) {
        float s = ob2[tid];
        for (int k = 0; k < HID; ++k) s += hm1[k] * oW2[k * HID + tid];
        hm2[tid] = tanhf(s);
    }
    __syncthreads();
    if (tid < NOUT) {
        float s = ob3[tid];
        for (int k = 0; k < HID; ++k) s += hm2[k] * oW3[k * NOUT + tid];
        out[(size_t)b * NOUT + tid] = s;
    }
}

extern "C" void kernel_launch(void* const* d_in, const int* in_sizes, int n_in,
                              void* d_out, int out_size, void* d_ws, size_t ws_size,
                              hipStream_t stream) {
    const float* x      = (const float*)d_in[0];
    const float* obs    = (const float*)d_in[1];
    const int*   src    = (const int*)d_in[2];
    /* d_in[3] = dst: structurally repeat(arange(N), DEG) — not needed */
    const int*   agent  = (const int*)d_in[4];
    const float* We     = (const float*)d_in[5];
    const float* be     = (const float*)d_in[6];
    const float* Wq     = (const float*)d_in[7];
    const float* bq     = (const float*)d_in[8];
    const float* Wk     = (const float*)d_in[9];
    const float* bk     = (const float*)d_in[10];
    const float* Wv     = (const float*)d_in[11];
    const float* bv     = (const float*)d_in[12];
    const float* Wo     = (const float*)d_in[13];
    const float* bo     = (const float*)d_in[14];
    const float* ln1_g  = (const float*)d_in[15];
    const float* ln1_b  = (const float*)d_in[16];
    const float* W1     = (const float*)d_in[17];
    const float* b1     = (const float*)d_in[18];
    const float* W2     = (const float*)d_in[19];
    const float* b2     = (const float*)d_in[20];
    const float* ln2_g  = (const float*)d_in[21];
    const float* ln2_b  = (const float*)d_in[22];
    const float* oW1    = (const float*)d_in[23];
    const float* ob1    = (const float*)d_in[24];
    const float* oW2    = (const float*)d_in[25];
    const float* ob2    = (const float*)d_in[26];
    const float* oW3    = (const float*)d_in[27];
    const float* ob3    = (const float*)d_in[28];

    float* out = (float*)d_out;
    char*  ws  = (char*)d_ws;

    const size_t hbytes = (size_t)NB * NN * 16;          // 4 MiB
    const size_t need   = 2 * hbytes + 32768 + 368640;

    if (ws_size >= need) {
        float4* hA     = (float4*)ws;
        float4* hB     = (float4*)(ws + hbytes);
        float*  fc1obs = (float*)(ws + 2 * hbytes);      // [128][45]

        gat0_mlp_kernel<<<2 * NB + NB, 1024, 0, stream>>>(x, hA, src,
            We, be, Wq, bq, Wk, bk, Wv, bv, Wo, bo, ln1_g, ln1_b, W1, b1, W2, b2,
            ln2_g, ln2_b, obs, oW1, fc1obs);

        gat_layer_kernel<<<2 * NB, 1024, 0, stream>>>(hA, hB, src, 1,
            Wq, bq, Wk, bk, Wv, bv, Wo, bo, ln1_g, ln1_b, W1, b1, W2, b2, ln2_g, ln2_b);
        gat_layer_kernel<<<2 * NB, 1024, 0, stream>>>(hB, hA, src, 2,
            Wq, bq, Wk, bk, Wv, bv, Wo, bo, ln1_g, ln1_b, W1, b1, W2, b2, ln2_g, ln2_b);

        final_kernel<<<NB, 64, 0, stream>>>(hA, src, agent,
            Wq, bq, Wk, bk, Wv, bv, Wo, bo, ln1_g, ln1_b, W1, b1, W2, b2, ln2_g, ln2_b,
            fc1obs, oW1, ob1, oW2, ob2, oW3, ob3, out);
    } else {
        float* gat_out = (float*)ws;
        float* partial = (float*)(ws + 2048);
        gat_single_kernel<<<NB, 1024, 0, stream>>>(x, src, agent, We, be, Wq, bq, Wk, bk,
                                                   Wv, bv, Wo, bo, ln1_g, ln1_b, W1, b1,
                                                   W2, b2, ln2_g, ln2_b, gat_out);
        mlp1_kernel<<<NB * KS, 256, 0, stream>>>(obs, gat_out, oW1, partial);
        mlp2_kernel<<<NB, 64, 0, stream>>>(partial, ob1, oW2, ob2, oW3, ob3, out);
    }
}

// Round 8
// 50.283 us; speedup vs baseline: 1.5087x; 1.3658x over previous
//
#include <hip/hip_runtime.h>
#include <hip/hip_bf16.h>

#define NB 128
#define NN 2048
#define DEG 16
#define EMBD 16
#define NL 4
#define OBSD 6154
#define HID 45
#define NOUT 15
#define KS 16
#define CH 385   // ceil(OBSD / KS)
#define RPB 4    // batch rows per mlp1 block
#define LOG2E 1.44269504f

__device__ __forceinline__ float frcp(float v) { return __builtin_amdgcn_rcpf(v); }

__device__ __forceinline__ uint32_t pk_bf16(float a, float b) {
    uint32_t ua = __float_as_uint(a); ua += 0x7fffu + ((ua >> 16) & 1u);
    uint32_t ub = __float_as_uint(b); ub += 0x7fffu + ((ub >> 16) & 1u);
    return (ua >> 16) | (ub & 0xffff0000u);
}
__device__ __forceinline__ float lo_bf(uint32_t u) { return __uint_as_float(u << 16); }
__device__ __forceinline__ float hi_bf(uint32_t u) { return __uint_as_float(u & 0xffff0000u); }

__device__ __forceinline__ void ln4(const float* p, const float* g, const float* bb, float* o) {
    float m = 0.25f * (p[0] + p[1] + p[2] + p[3]);
    float var = 0.f;
#pragma unroll
    for (int j = 0; j < 4; ++j) { float d = p[j] - m; var += d * d; }
    var *= 0.25f;
    float rs = rsqrtf(var + 1e-5f);
#pragma unroll
    for (int j = 0; j < 4; ++j) o[j] = g[j] * (p[j] - m) * rs + bb[j];
}

// residual tail after attention message: Wo + LN1 + FFN + LN2 (updates hh in place)
__device__ __forceinline__ void node_tail(float* hh, const float* msg,
    const float* wo, const float* bol, const float* g1, const float* be1,
    const float* w1, const float* b1l, const float* w2, const float* b2l,
    const float* g2, const float* be2)
{
    float pre[4];
#pragma unroll
    for (int j = 0; j < 4; ++j) {
        float s = bol[j];
#pragma unroll
        for (int i = 0; i < 4; ++i) s += msg[i] * wo[i * 4 + j];
        pre[j] = hh[j] + s;
    }
    float hn[4];
    ln4(pre, g1, be1, hn);
    float mid[8];
#pragma unroll
    for (int j = 0; j < 8; ++j) {
        float s = b1l[j];
#pragma unroll
        for (int i = 0; i < 4; ++i) s += hn[i] * w1[i * 8 + j];
        mid[j] = fmaxf(s, 0.f);
    }
    float pre2[4];
#pragma unroll
    for (int j = 0; j < 4; ++j) {
        float s = b2l[j];
#pragma unroll
        for (int i = 0; i < 8; ++i) s += mid[i] * w2[i * 4 + j];
        pre2[j] = hn[j] + s;
    }
    ln4(pre2, g2, be2, hh);
}

// shared gather + tail body for a layer (kv staged in LDS, q2 prescaled)
__device__ __forceinline__ void gather_tail(const uint4* kv, const int* su,
    const float* q2, float* hh, int l,
    const float* Wo, const float* bo, const float* ln1_g, const float* ln1_b,
    const float* W1, const float* b1, const float* W2, const float* b2,
    const float* ln2_g, const float* ln2_b)
{
    float z[4] = {0.f, 0.f, 0.f, 0.f}, wa[4] = {0.f, 0.f, 0.f, 0.f};
#pragma unroll
    for (int eb = 0; eb < 4; ++eb) {
        uint4 t0 = kv[su[eb * 4 + 0]];
        uint4 t1 = kv[su[eb * 4 + 1]];
        uint4 t2 = kv[su[eb * 4 + 2]];
        uint4 t3 = kv[su[eb * 4 + 3]];
        float p;
        p = __builtin_amdgcn_exp2f(q2[0] * lo_bf(t0.x)); z[0] += p; wa[0] += p * lo_bf(t0.z);
        p = __builtin_amdgcn_exp2f(q2[1] * hi_bf(t0.x)); z[1] += p; wa[1] += p * hi_bf(t0.z);
        p = __builtin_amdgcn_exp2f(q2[2] * lo_bf(t0.y)); z[2] += p; wa[2] += p * lo_bf(t0.w);
        p = __builtin_amdgcn_exp2f(q2[3] * hi_bf(t0.y)); z[3] += p; wa[3] += p * hi_bf(t0.w);
        p = __builtin_amdgcn_exp2f(q2[0] * lo_bf(t1.x)); z[0] += p; wa[0] += p * lo_bf(t1.z);
        p = __builtin_amdgcn_exp2f(q2[1] * hi_bf(t1.x)); z[1] += p; wa[1] += p * hi_bf(t1.z);
        p = __builtin_amdgcn_exp2f(q2[2] * lo_bf(t1.y)); z[2] += p; wa[2] += p * lo_bf(t1.w);
        p = __builtin_amdgcn_exp2f(q2[3] * hi_bf(t1.y)); z[3] += p; wa[3] += p * hi_bf(t1.w);
        p = __builtin_amdgcn_exp2f(q2[0] * lo_bf(t2.x)); z[0] += p; wa[0] += p * lo_bf(t2.z);
        p = __builtin_amdgcn_exp2f(q2[1] * hi_bf(t2.x)); z[1] += p; wa[1] += p * hi_bf(t2.z);
        p = __builtin_amdgcn_exp2f(q2[2] * lo_bf(t2.y)); z[2] += p; wa[2] += p * lo_bf(t2.w);
        p = __builtin_amdgcn_exp2f(q2[3] * hi_bf(t2.y)); z[3] += p; wa[3] += p * hi_bf(t2.w);
        p = __builtin_amdgcn_exp2f(q2[0] * lo_bf(t3.x)); z[0] += p; wa[0] += p * lo_bf(t3.z);
        p = __builtin_amdgcn_exp2f(q2[1] * hi_bf(t3.x)); z[1] += p; wa[1] += p * hi_bf(t3.z);
        p = __builtin_amdgcn_exp2f(q2[2] * lo_bf(t3.y)); z[2] += p; wa[2] += p * lo_bf(t3.w);
        p = __builtin_amdgcn_exp2f(q2[3] * hi_bf(t3.y)); z[3] += p; wa[3] += p * hi_bf(t3.w);
    }
    float msg[4];
#pragma unroll
    for (int j = 0; j < 4; ++j) msg[j] = wa[j] * frcp(z[j] + 1e-6f);
    node_tail(hh, msg, Wo + l * 16, bo + l * 4, ln1_g + l * 4, ln1_b + l * 4,
              W1 + l * 32, b1 + l * 8, W2 + l * 32, b2 + l * 4,
              ln2_g + l * 4, ln2_b + l * 4);
}

// ============ K0: GAT layer 0 with embed fused. 2 blocks/graph ============
__global__ __launch_bounds__(1024) void gat_layer0_kernel(
    const float* __restrict__ x, float4* __restrict__ hout,
    const int* __restrict__ src,
    const float* __restrict__ We, const float* __restrict__ be,
    const float* __restrict__ Wq, const float* __restrict__ bq,
    const float* __restrict__ Wk, const float* __restrict__ bk,
    const float* __restrict__ Wv, const float* __restrict__ bv,
    const float* __restrict__ Wo, const float* __restrict__ bo,
    const float* __restrict__ ln1_g, const float* __restrict__ ln1_b,
    const float* __restrict__ W1, const float* __restrict__ b1,
    const float* __restrict__ W2, const float* __restrict__ b2,
    const float* __restrict__ ln2_g, const float* __restrict__ ln2_b)
{
    __shared__ uint4 kv[NN];
    const int bid = blockIdx.x;
    const int b = bid >> 1, half = bid & 1;
    const int tid = threadIdx.x;
    const int own = half * 1024 + tid;
    const int l = 0;

    int su[16];
    {
        const int4* sp = reinterpret_cast<const int4*>(src + own * DEG);
#pragma unroll
        for (int t4 = 0; t4 < 4; ++t4) {
            int4 s4 = sp[t4];
            su[t4 * 4 + 0] = s4.x; su[t4 * 4 + 1] = s4.y;
            su[t4 * 4 + 2] = s4.z; su[t4 * 4 + 3] = s4.w;
        }
    }

    float hv[2][4];
#pragma unroll
    for (int c = 0; c < 2; ++c) {
        const float4* xr = reinterpret_cast<const float4*>(
            x + ((size_t)b * NN + c * 1024 + tid) * EMBD);
        float xv[16];
#pragma unroll
        for (int t4 = 0; t4 < 4; ++t4) {
            float4 t = xr[t4];
            xv[t4 * 4 + 0] = t.x; xv[t4 * 4 + 1] = t.y;
            xv[t4 * 4 + 2] = t.z; xv[t4 * 4 + 3] = t.w;
        }
#pragma unroll
        for (int j = 0; j < 4; ++j) {
            float s = be[j];
#pragma unroll
            for (int i = 0; i < 16; ++i) s += xv[i] * We[i * 4 + j];
            hv[c][j] = s;
        }
    }

    const float* wk = Wk + l * 16; const float* bkl = bk + l * 4;
    const float* wv = Wv + l * 16; const float* bvl = bv + l * 4;
#pragma unroll
    for (int c = 0; c < 2; ++c) {
        float kk[4], vv[4];
#pragma unroll
        for (int j = 0; j < 4; ++j) {
            float sk = bkl[j], sv = bvl[j];
#pragma unroll
            for (int i = 0; i < 4; ++i) {
                sk += hv[c][i] * wk[i * 4 + j];
                sv += hv[c][i] * wv[i * 4 + j];
            }
            kk[j] = sk; vv[j] = sv;
        }
        kv[c * 1024 + tid] = make_uint4(pk_bf16(kk[0], kk[1]), pk_bf16(kk[2], kk[3]),
                                        pk_bf16(vv[0], vv[1]), pk_bf16(vv[2], vv[3]));
    }

    float hh[4] = {hv[half][0], hv[half][1], hv[half][2], hv[half][3]};
    float q2[4];
    {
        const float* wq = Wq + l * 16; const float* bql = bq + l * 4;
#pragma unroll
        for (int j = 0; j < 4; ++j) {
            float sq = bql[j];
#pragma unroll
            for (int i = 0; i < 4; ++i) sq += hh[i] * wq[i * 4 + j];
            q2[j] = sq * LOG2E;
        }
    }
    __syncthreads();

    gather_tail(kv, su, q2, hh, l, Wo, bo, ln1_g, ln1_b, W1, b1, W2, b2, ln2_g, ln2_b);

    hout[(size_t)b * NN + own] = make_float4(hh[0], hh[1], hh[2], hh[3]);
}

// ============ K1/K2: GAT layer l (l = 1, 2), 2 blocks/graph ============
__global__ __launch_bounds__(1024) void gat_layer_kernel(
    const float4* __restrict__ hin, float4* __restrict__ hout,
    const int* __restrict__ src, const int l,
    const float* __restrict__ Wq, const float* __restrict__ bq,
    const float* __restrict__ Wk, const float* __restrict__ bk,
    const float* __restrict__ Wv, const float* __restrict__ bv,
    const float* __restrict__ Wo, const float* __restrict__ bo,
    const float* __restrict__ ln1_g, const float* __restrict__ ln1_b,
    const float* __restrict__ W1, const float* __restrict__ b1,
    const float* __restrict__ W2, const float* __restrict__ b2,
    const float* __restrict__ ln2_g, const float* __restrict__ ln2_b)
{
    __shared__ uint4 kv[NN];
    const int bid = blockIdx.x;
    const int b = bid >> 1, half = bid & 1;
    const int tid = threadIdx.x;
    const int own = half * 1024 + tid;

    int su[16];
    {
        const int4* sp = reinterpret_cast<const int4*>(src + own * DEG);
#pragma unroll
        for (int t4 = 0; t4 < 4; ++t4) {
            int4 s4 = sp[t4];
            su[t4 * 4 + 0] = s4.x; su[t4 * 4 + 1] = s4.y;
            su[t4 * 4 + 2] = s4.z; su[t4 * 4 + 3] = s4.w;
        }
    }

    const float4* hb = hin + (size_t)b * NN;
    float hv[2][4];
    {
        float4 a0 = hb[tid];
        float4 a1 = hb[1024 + tid];
        hv[0][0] = a0.x; hv[0][1] = a0.y; hv[0][2] = a0.z; hv[0][3] = a0.w;
        hv[1][0] = a1.x; hv[1][1] = a1.y; hv[1][2] = a1.z; hv[1][3] = a1.w;
    }

    const float* wk = Wk + l * 16; const float* bkl = bk + l * 4;
    const float* wv = Wv + l * 16; const float* bvl = bv + l * 4;
#pragma unroll
    for (int c = 0; c < 2; ++c) {
        float kk[4], vv[4];
#pragma unroll
        for (int j = 0; j < 4; ++j) {
            float sk = bkl[j], sv = bvl[j];
#pragma unroll
            for (int i = 0; i < 4; ++i) {
                sk += hv[c][i] * wk[i * 4 + j];
                sv += hv[c][i] * wv[i * 4 + j];
            }
            kk[j] = sk; vv[j] = sv;
        }
        kv[c * 1024 + tid] = make_uint4(pk_bf16(kk[0], kk[1]), pk_bf16(kk[2], kk[3]),
                                        pk_bf16(vv[0], vv[1]), pk_bf16(vv[2], vv[3]));
    }

    float hh[4] = {hv[half][0], hv[half][1], hv[half][2], hv[half][3]};
    float q2[4];
    {
        const float* wq = Wq + l * 16; const float* bql = bq + l * 4;
#pragma unroll
        for (int j = 0; j < 4; ++j) {
            float sq = bql[j];
#pragma unroll
            for (int i = 0; i < 4; ++i) sq += hh[i] * wq[i * 4 + j];
            q2[j] = sq * LOG2E;
        }
    }
    __syncthreads();

    gather_tail(kv, su, q2, hh, l, Wo, bo, ln1_g, ln1_b, W1, b1, W2, b2, ln2_g, ln2_b);

    hout[(size_t)b * NN + own] = make_float4(hh[0], hh[1], hh[2], hh[3]);
}

// ======== mlp1b: split-K fc1 obs-part, RPB batch rows per block ========
// grid: (NB/RPB) * KS = 32*16 = 512 blocks, 256 threads
__global__ __launch_bounds__(256) void mlp1b_kernel(
    const float* __restrict__ obs, const float* __restrict__ oW1,
    float* __restrict__ partial)
{
    __shared__ float red[4][RPB][HID];
    const int blk = blockIdx.x;
    const int rg = blk >> 4;          // row group
    const int ks = blk & (KS - 1);
    const int tid = threadIdx.x;
    const int w = tid >> 6, lane = tid & 63;

    const int c0 = ks * CH;
    const int c1 = min(c0 + CH, OBSD);
    const int wl = (c1 - c0 + 3) >> 2;
    const int s0 = c0 + w * wl;
    const int s1 = min(s0 + wl, c1);
    const float* ob0 = obs + (size_t)(rg * RPB) * OBSD;

    if (lane < HID) {
        float acc[RPB] = {0.f, 0.f, 0.f, 0.f};
#pragma unroll 4
        for (int i = s0; i < s1; ++i) {
            float wv = oW1[(size_t)(i + 4) * HID + lane];
#pragma unroll
            for (int r = 0; r < RPB; ++r)
                acc[r] += ob0[(size_t)r * OBSD + i] * wv;
        }
#pragma unroll
        for (int r = 0; r < RPB; ++r) red[w][r][lane] = acc[r];
    }
    __syncthreads();
    for (int idx = tid; idx < RPB * HID; idx += 256) {
        const int r = idx / HID, j = idx % HID;
        partial[(size_t)((rg * RPB + r) * KS + ks) * HID + j] =
            red[0][r][j] + red[1][r][j] + red[2][r][j] + red[3][r][j];
    }
}

// ===== K3: final GAT layer at agent nodes + MLP head. 1 wave per batch row =====
__global__ __launch_bounds__(64) void final_kernel(
    const float4* __restrict__ h3, const int* __restrict__ src,
    const int* __restrict__ agent_nodes,
    const float* __restrict__ Wq, const float* __restrict__ bq,
    const float* __restrict__ Wk, const float* __restrict__ bk,
    const float* __restrict__ Wv, const float* __restrict__ bv,
    const float* __restrict__ Wo, const float* __restrict__ bo,
    const float* __restrict__ ln1_g, const float* __restrict__ ln1_b,
    const float* __restrict__ W1, const float* __restrict__ b1,
    const float* __restrict__ W2, const float* __restrict__ b2,
    const float* __restrict__ ln2_g, const float* __restrict__ ln2_b,
    const float* __restrict__ partial, const float* __restrict__ oW1,
    const float* __restrict__ ob1,
    const float* __restrict__ oW2, const float* __restrict__ ob2,
    const float* __restrict__ oW3, const float* __restrict__ ob3,
    float* __restrict__ out)
{
    __shared__ float hm1s[HID];
    __shared__ float hm2s[HID];
    const int b = blockIdx.x;
    const int lane = threadIdx.x;
    const int e = lane >> 2, hd = lane & 3;   // edge, head
    const int l = NL - 1;

    const int ag = agent_nodes[b];
    const float4 ha4 = h3[(size_t)b * NN + ag];
    const float ha[4] = {ha4.x, ha4.y, ha4.z, ha4.w};

    float qh;
    {
        const float* wq = Wq + l * 16;
        qh = bq[l * 4 + hd];
#pragma unroll
        for (int i = 0; i < 4; ++i) qh += ha[i] * wq[i * 4 + hd];
        qh *= LOG2E;
    }

    const int ne = src[ag * DEG + e];
    const float4 hn4 = h3[(size_t)b * NN + ne];
    float kh, vh;
    {
        const float* wk = Wk + l * 16; const float* wv = Wv + l * 16;
        kh = bk[l * 4 + hd]; vh = bv[l * 4 + hd];
#pragma unroll
        for (int i = 0; i < 4; ++i) {
            const float hni = (i == 0) ? hn4.x : (i == 1) ? hn4.y : (i == 2) ? hn4.z : hn4.w;
            kh += hni * wk[i * 4 + hd];
            vh += hni * wv[i * 4 + hd];
        }
    }

    float p = __builtin_amdgcn_exp2f(qh * kh);
    float z = p, wv_s = p * vh;
#pragma unroll
    for (int m = 4; m <= 32; m <<= 1) {
        z    += __shfl_xor(z, m, 64);
        wv_s += __shfl_xor(wv_s, m, 64);
    }
    float msg_h = wv_s * frcp(z + 1e-6f);

    float msg[4];
#pragma unroll
    for (int j = 0; j < 4; ++j) msg[j] = __shfl(msg_h, (lane & ~3) + j, 64);

    float hh[4] = {ha[0], ha[1], ha[2], ha[3]};
    node_tail(hh, msg, Wo + l * 16, bo + l * 4, ln1_g + l * 4, ln1_b + l * 4,
              W1 + l * 32, b1 + l * 8, W2 + l * 32, b2 + l * 4,
              ln2_g + l * 4, ln2_b + l * 4);

    // MLP head: fc1 (obs part from partials) -> tanh -> fc2 -> tanh -> fc3
    if (lane < HID) {
        float s = ob1[lane];
        const float* pp = partial + (size_t)b * KS * HID + lane;
#pragma unroll
        for (int ks = 0; ks < KS; ++ks) s += pp[ks * HID];
#pragma unroll
        for (int k = 0; k < 4; ++k) s += hh[k] * oW1[k * HID + lane];
        hm1s[lane] = tanhf(s);
    }
    __syncthreads();
    if (lane < HID) {
        float s = ob2[lane];
        for (int k = 0; k < HID; ++k) s += hm1s[k] * oW2[k * HID + lane];
        hm2s[lane] = tanhf(s);
    }
    __syncthreads();
    if (lane < NOUT) {
        float s = ob3[lane];
        for (int k = 0; k < HID; ++k) s += hm2s[k] * oW3[k * NOUT + lane];
        out[(size_t)b * NOUT + lane] = s;
    }
}

// ===================== fallback: one block per graph + split-K mlp =====================
__global__ __launch_bounds__(1024) void gat_single_kernel(
    const float* __restrict__ x, const int* __restrict__ src,
    const int* __restrict__ agent_nodes,
    const float* __restrict__ We, const float* __restrict__ be,
    const float* __restrict__ Wq, const float* __restrict__ bq,
    const float* __restrict__ Wk, const float* __restrict__ bk,
    const float* __restrict__ Wv, const float* __restrict__ bv,
    const float* __restrict__ Wo, const float* __restrict__ bo,
    const float* __restrict__ ln1_g, const float* __restrict__ ln1_b,
    const float* __restrict__ W1, const float* __restrict__ b1,
    const float* __restrict__ W2, const float* __restrict__ b2,
    const float* __restrict__ ln2_g, const float* __restrict__ ln2_b,
    float* __restrict__ gat_out)
{
    __shared__ uint4 kv[NN];
    const int b = blockIdx.x;
    const int tid = threadIdx.x;
    float h[2][4];
#pragma unroll
    for (int u = 0; u < 2; ++u) {
        const int n = tid + u * 1024;
        const float4* xr = reinterpret_cast<const float4*>(x + ((size_t)b * NN + n) * EMBD);
        float xv[16];
#pragma unroll
        for (int t4 = 0; t4 < 4; ++t4) {
            float4 t = xr[t4];
            xv[t4 * 4 + 0] = t.x; xv[t4 * 4 + 1] = t.y;
            xv[t4 * 4 + 2] = t.z; xv[t4 * 4 + 3] = t.w;
        }
#pragma unroll
        for (int j = 0; j < 4; ++j) {
            float s = be[j];
#pragma unroll
            for (int i = 0; i < 16; ++i) s += xv[i] * We[i * 4 + j];
            h[u][j] = s;
        }
    }
    for (int l = 0; l < NL; ++l) {
        float q2[2][4];
        const float* wq = Wq + l * 16; const float* bql = bq + l * 4;
        const float* wk = Wk + l * 16; const float* bkl = bk + l * 4;
        const float* wv = Wv + l * 16; const float* bvl = bv + l * 4;
#pragma unroll
        for (int u = 0; u < 2; ++u) {
            const int n = tid + u * 1024;
            float kk[4], vv[4];
#pragma unroll
            for (int j = 0; j < 4; ++j) {
                float sq = bql[j], sk = bkl[j], sv = bvl[j];
#pragma unroll
                for (int i = 0; i < 4; ++i) {
                    sq += h[u][i] * wq[i * 4 + j];
                    sk += h[u][i] * wk[i * 4 + j];
                    sv += h[u][i] * wv[i * 4 + j];
                }
                q2[u][j] = sq * LOG2E; kk[j] = sk; vv[j] = sv;
            }
            kv[n] = make_uint4(pk_bf16(kk[0], kk[1]), pk_bf16(kk[2], kk[3]),
                               pk_bf16(vv[0], vv[1]), pk_bf16(vv[2], vv[3]));
        }
        __syncthreads();
#pragma unroll
        for (int u = 0; u < 2; ++u) {
            const int n = tid + u * 1024;
            int su[16];
            const int4* sp = reinterpret_cast<const int4*>(src + n * DEG);
#pragma unroll
            for (int t4 = 0; t4 < 4; ++t4) {
                int4 s4 = sp[t4];
                su[t4 * 4 + 0] = s4.x; su[t4 * 4 + 1] = s4.y;
                su[t4 * 4 + 2] = s4.z; su[t4 * 4 + 3] = s4.w;
            }
            gather_tail(kv, su, q2[u], h[u], l, Wo, bo, ln1_g, ln1_b,
                        W1, b1, W2, b2, ln2_g, ln2_b);
        }
        __syncthreads();
    }
    const int agent = agent_nodes[b];
#pragma unroll
    for (int u = 0; u < 2; ++u) {
        if (tid + u * 1024 == agent) {
#pragma unroll
            for (int j = 0; j < 4; ++j) gat_out[b * 4 + j] = h[u][j];
        }
    }
}

__global__ __launch_bounds__(64) void mlp2_fb_kernel(
    const float* __restrict__ partial, const float* __restrict__ gat,
    const float* __restrict__ oW1, const float* __restrict__ ob1,
    const float* __restrict__ oW2, const float* __restrict__ ob2,
    const float* __restrict__ oW3, const float* __restrict__ ob3,
    float* __restrict__ out)
{
    __shared__ float hm1[HID], hm2[HID];
    const int b = blockIdx.x;
    const int tid = threadIdx.x;
    if (tid < HID) {
        float s = ob1[tid];
        const float* pp = partial + (size_t)b * KS * HID + tid;
#pragma unroll
        for (int ks = 0; ks < KS; ++ks) s += pp[ks * HID];
#pragma unroll
        for (int k = 0; k < 4; ++k) s += gat[b * 4 + k] * oW1[k * HID + tid];
        hm1[tid] = tanhf(s);
    }
    __syncthreads();
    if (tid < HID) {
        float s = ob2[tid];
        for (int k = 0; k < HID; ++k) s += hm1[k] * oW2[k * HID + tid];
        hm2[tid] = tanhf(s);
    }
    __syncthreads();
    if (tid < NOUT) {
        float s = ob3[tid];
        for (int k = 0; k < HID; ++k) s += hm2[k] * oW3[k * NOUT + tid];
        out[(size_t)b * NOUT + tid] = s;
    }
}

extern "C" void kernel_launch(void* const* d_in, const int* in_sizes, int n_in,
                              void* d_out, int out_size, void* d_ws, size_t ws_size,
                              hipStream_t stream) {
    const float* x      = (const float*)d_in[0];
    const float* obs    = (const float*)d_in[1];
    const int*   src    = (const int*)d_in[2];
    /* d_in[3] = dst: structurally repeat(arange(N), DEG) — not needed */
    const int*   agent  = (const int*)d_in[4];
    const float* We     = (const float*)d_in[5];
    const float* be     = (const float*)d_in[6];
    const float* Wq     = (const float*)d_in[7];
    const float* bq     = (const float*)d_in[8];
    const float* Wk     = (const float*)d_in[9];
    const float* bk     = (const float*)d_in[10];
    const float* Wv     = (const float*)d_in[11];
    const float* bv     = (const float*)d_in[12];
    const float* Wo     = (const float*)d_in[13];
    const float* bo     = (const float*)d_in[14];
    const float* ln1_g  = (const float*)d_in[15];
    const float* ln1_b  = (const float*)d_in[16];
    const float* W1     = (const float*)d_in[17];
    const float* b1     = (const float*)d_in[18];
    const float* W2     = (const float*)d_in[19];
    const float* b2     = (const float*)d_in[20];
    const float* ln2_g  = (const float*)d_in[21];
    const float* ln2_b  = (const float*)d_in[22];
    const float* oW1    = (const float*)d_in[23];
    const float* ob1    = (const float*)d_in[24];
    const float* oW2    = (const float*)d_in[25];
    const float* ob2    = (const float*)d_in[26];
    const float* oW3    = (const float*)d_in[27];
    const float* ob3    = (const float*)d_in[28];

    float* out = (float*)d_out;
    char*  ws  = (char*)d_ws;

    const size_t hbytes = (size_t)NB * NN * 16;          // 4 MiB
    const size_t need   = 2 * hbytes + 368640 + 4096;

    if (ws_size >= need) {
        float4* hA      = (float4*)ws;
        float4* hB      = (float4*)(ws + hbytes);
        float*  partial = (float*)(ws + 2 * hbytes);     // [128][16][45]

        mlp1b_kernel<<<(NB / RPB) * KS, 256, 0, stream>>>(obs, oW1, partial);

        gat_layer0_kernel<<<2 * NB, 1024, 0, stream>>>(x, hA, src,
            We, be, Wq, bq, Wk, bk, Wv, bv, Wo, bo, ln1_g, ln1_b, W1, b1, W2, b2,
            ln2_g, ln2_b);
        gat_layer_kernel<<<2 * NB, 1024, 0, stream>>>(hA, hB, src, 1,
            Wq, bq, Wk, bk, Wv, bv, Wo, bo, ln1_g, ln1_b, W1, b1, W2, b2, ln2_g, ln2_b);
        gat_layer_kernel<<<2 * NB, 1024, 0, stream>>>(hB, hA, src, 2,
            Wq, bq, Wk, bk, Wv, bv, Wo, bo, ln1_g, ln1_b, W1, b1, W2, b2, ln2_g, ln2_b);

        final_kernel<<<NB, 64, 0, stream>>>(hA, src, agent,
            Wq, bq, Wk, bk, Wv, bv, Wo, bo, ln1_g, ln1_b, W1, b1, W2, b2, ln2_g, ln2_b,
            partial, oW1, ob1, oW2, ob2, oW3, ob3, out);
    } else {
        float* gat_out = (float*)ws;
        float* partial = (float*)(ws + 2048);
        gat_single_kernel<<<NB, 1024, 0, stream>>>(x, src, agent, We, be, Wq, bq, Wk, bk,
                                                   Wv, bv, Wo, bo, ln1_g, ln1_b, W1, b1,
                                                   W2, b2, ln2_g, ln2_b, gat_out);
        mlp1b_kernel<<<(NB / RPB) * KS, 256, 0, stream>>>(obs, oW1, partial);
        mlp2_fb_kernel<<<NB, 64, 0, stream>>>(partial, gat_out, oW1, ob1, oW2, ob2,
                                              oW3, ob3, out);
    }
}

// Round 9
// 44.117 us; speedup vs baseline: 1.7196x; 1.1398x over previous
//
#include <hip/hip_runtime.h>
#include <hip/hip_bf16.h>

#define NB 128
#define NN 2048
#define DEG 16
#define EMBD 16
#define NL 4
#define OBSD 6154
#define HID 45
#define NOUT 15
#define KS 16
#define CH 385   // ceil(OBSD / KS)
#define RPB 4    // batch rows per mlp1 block
#define LOG2E 1.44269504f

__device__ __forceinline__ float frcp(float v) { return __builtin_amdgcn_rcpf(v); }

__device__ __forceinline__ uint32_t pk_bf16(float a, float b) {
    uint32_t ua = __float_as_uint(a); ua += 0x7fffu + ((ua >> 16) & 1u);
    uint32_t ub = __float_as_uint(b); ub += 0x7fffu + ((ub >> 16) & 1u);
    return (ua >> 16) | (ub & 0xffff0000u);
}
__device__ __forceinline__ float lo_bf(uint32_t u) { return __uint_as_float(u << 16); }
__device__ __forceinline__ float hi_bf(uint32_t u) { return __uint_as_float(u & 0xffff0000u); }

__device__ __forceinline__ void ln4(const float* p, const float* g, const float* bb, float* o) {
    float m = 0.25f * (p[0] + p[1] + p[2] + p[3]);
    float var = 0.f;
#pragma unroll
    for (int j = 0; j < 4; ++j) { float d = p[j] - m; var += d * d; }
    var *= 0.25f;
    float rs = rsqrtf(var + 1e-5f);
#pragma unroll
    for (int j = 0; j < 4; ++j) o[j] = g[j] * (p[j] - m) * rs + bb[j];
}

// residual tail after attention message: Wo + LN1 + FFN + LN2 (updates hh in place)
__device__ __forceinline__ void node_tail(float* hh, const float* msg,
    const float* wo, const float* bol, const float* g1, const float* be1,
    const float* w1, const float* b1l, const float* w2, const float* b2l,
    const float* g2, const float* be2)
{
    float pre[4];
#pragma unroll
    for (int j = 0; j < 4; ++j) {
        float s = bol[j];
#pragma unroll
        for (int i = 0; i < 4; ++i) s += msg[i] * wo[i * 4 + j];
        pre[j] = hh[j] + s;
    }
    float hn[4];
    ln4(pre, g1, be1, hn);
    float mid[8];
#pragma unroll
    for (int j = 0; j < 8; ++j) {
        float s = b1l[j];
#pragma unroll
        for (int i = 0; i < 4; ++i) s += hn[i] * w1[i * 8 + j];
        mid[j] = fmaxf(s, 0.f);
    }
    float pre2[4];
#pragma unroll
    for (int j = 0; j < 4; ++j) {
        float s = b2l[j];
#pragma unroll
        for (int i = 0; i < 8; ++i) s += mid[i] * w2[i * 4 + j];
        pre2[j] = hn[j] + s;
    }
    ln4(pre2, g2, be2, hh);
}

// shared gather + tail body for a layer (kv staged in LDS, q2 prescaled)
__device__ __forceinline__ void gather_tail(const uint4* kv, const int* su,
    const float* q2, float* hh, int l,
    const float* Wo, const float* bo, const float* ln1_g, const float* ln1_b,
    const float* W1, const float* b1, const float* W2, const float* b2,
    const float* ln2_g, const float* ln2_b)
{
    float z[4] = {0.f, 0.f, 0.f, 0.f}, wa[4] = {0.f, 0.f, 0.f, 0.f};
#pragma unroll
    for (int eb = 0; eb < 4; ++eb) {
        uint4 t0 = kv[su[eb * 4 + 0]];
        uint4 t1 = kv[su[eb * 4 + 1]];
        uint4 t2 = kv[su[eb * 4 + 2]];
        uint4 t3 = kv[su[eb * 4 + 3]];
        float p;
        p = __builtin_amdgcn_exp2f(q2[0] * lo_bf(t0.x)); z[0] += p; wa[0] += p * lo_bf(t0.z);
        p = __builtin_amdgcn_exp2f(q2[1] * hi_bf(t0.x)); z[1] += p; wa[1] += p * hi_bf(t0.z);
        p = __builtin_amdgcn_exp2f(q2[2] * lo_bf(t0.y)); z[2] += p; wa[2] += p * lo_bf(t0.w);
        p = __builtin_amdgcn_exp2f(q2[3] * hi_bf(t0.y)); z[3] += p; wa[3] += p * hi_bf(t0.w);
        p = __builtin_amdgcn_exp2f(q2[0] * lo_bf(t1.x)); z[0] += p; wa[0] += p * lo_bf(t1.z);
        p = __builtin_amdgcn_exp2f(q2[1] * hi_bf(t1.x)); z[1] += p; wa[1] += p * hi_bf(t1.z);
        p = __builtin_amdgcn_exp2f(q2[2] * lo_bf(t1.y)); z[2] += p; wa[2] += p * lo_bf(t1.w);
        p = __builtin_amdgcn_exp2f(q2[3] * hi_bf(t1.y)); z[3] += p; wa[3] += p * hi_bf(t1.w);
        p = __builtin_amdgcn_exp2f(q2[0] * lo_bf(t2.x)); z[0] += p; wa[0] += p * lo_bf(t2.z);
        p = __builtin_amdgcn_exp2f(q2[1] * hi_bf(t2.x)); z[1] += p; wa[1] += p * hi_bf(t2.z);
        p = __builtin_amdgcn_exp2f(q2[2] * lo_bf(t2.y)); z[2] += p; wa[2] += p * lo_bf(t2.w);
        p = __builtin_amdgcn_exp2f(q2[3] * hi_bf(t2.y)); z[3] += p; wa[3] += p * hi_bf(t2.w);
        p = __builtin_amdgcn_exp2f(q2[0] * lo_bf(t3.x)); z[0] += p; wa[0] += p * lo_bf(t3.z);
        p = __builtin_amdgcn_exp2f(q2[1] * hi_bf(t3.x)); z[1] += p; wa[1] += p * hi_bf(t3.z);
        p = __builtin_amdgcn_exp2f(q2[2] * lo_bf(t3.y)); z[2] += p; wa[2] += p * lo_bf(t3.w);
        p = __builtin_amdgcn_exp2f(q2[3] * hi_bf(t3.y)); z[3] += p; wa[3] += p * hi_bf(t3.w);
    }
    float msg[4];
#pragma unroll
    for (int j = 0; j < 4; ++j) msg[j] = wa[j] * frcp(z[j] + 1e-6f);
    node_tail(hh, msg, Wo + l * 16, bo + l * 4, ln1_g + l * 4, ln1_b + l * 4,
              W1 + l * 32, b1 + l * 8, W2 + l * 32, b2 + l * 4,
              ln2_g + l * 4, ln2_b + l * 4);
}

// ============ K0: GAT layer 0 with embed fused. 2 blocks/graph ============
__global__ __launch_bounds__(1024) void gat_layer0_kernel(
    const float* __restrict__ x, float4* __restrict__ hout,
    const int* __restrict__ src,
    const float* __restrict__ We, const float* __restrict__ be,
    const float* __restrict__ Wq, const float* __restrict__ bq,
    const float* __restrict__ Wk, const float* __restrict__ bk,
    const float* __restrict__ Wv, const float* __restrict__ bv,
    const float* __restrict__ Wo, const float* __restrict__ bo,
    const float* __restrict__ ln1_g, const float* __restrict__ ln1_b,
    const float* __restrict__ W1, const float* __restrict__ b1,
    const float* __restrict__ W2, const float* __restrict__ b2,
    const float* __restrict__ ln2_g, const float* __restrict__ ln2_b)
{
    __shared__ uint4 kv[NN];
    const int bid = blockIdx.x;
    const int b = bid >> 1, half = bid & 1;
    const int tid = threadIdx.x;
    const int own = half * 1024 + tid;
    const int l = 0;

    int su[16];
    {
        const int4* sp = reinterpret_cast<const int4*>(src + own * DEG);
#pragma unroll
        for (int t4 = 0; t4 < 4; ++t4) {
            int4 s4 = sp[t4];
            su[t4 * 4 + 0] = s4.x; su[t4 * 4 + 1] = s4.y;
            su[t4 * 4 + 2] = s4.z; su[t4 * 4 + 3] = s4.w;
        }
    }

    float hv[2][4];
#pragma unroll
    for (int c = 0; c < 2; ++c) {
        const float4* xr = reinterpret_cast<const float4*>(
            x + ((size_t)b * NN + c * 1024 + tid) * EMBD);
        float xv[16];
#pragma unroll
        for (int t4 = 0; t4 < 4; ++t4) {
            float4 t = xr[t4];
            xv[t4 * 4 + 0] = t.x; xv[t4 * 4 + 1] = t.y;
            xv[t4 * 4 + 2] = t.z; xv[t4 * 4 + 3] = t.w;
        }
#pragma unroll
        for (int j = 0; j < 4; ++j) {
            float s = be[j];
#pragma unroll
            for (int i = 0; i < 16; ++i) s += xv[i] * We[i * 4 + j];
            hv[c][j] = s;
        }
    }

    const float* wk = Wk + l * 16; const float* bkl = bk + l * 4;
    const float* wv = Wv + l * 16; const float* bvl = bv + l * 4;
#pragma unroll
    for (int c = 0; c < 2; ++c) {
        float kk[4], vv[4];
#pragma unroll
        for (int j = 0; j < 4; ++j) {
            float sk = bkl[j], sv = bvl[j];
#pragma unroll
            for (int i = 0; i < 4; ++i) {
                sk += hv[c][i] * wk[i * 4 + j];
                sv += hv[c][i] * wv[i * 4 + j];
            }
            kk[j] = sk; vv[j] = sv;
        }
        kv[c * 1024 + tid] = make_uint4(pk_bf16(kk[0], kk[1]), pk_bf16(kk[2], kk[3]),
                                        pk_bf16(vv[0], vv[1]), pk_bf16(vv[2], vv[3]));
    }

    float hh[4] = {hv[half][0], hv[half][1], hv[half][2], hv[half][3]};
    float q2[4];
    {
        const float* wq = Wq + l * 16; const float* bql = bq + l * 4;
#pragma unroll
        for (int j = 0; j < 4; ++j) {
            float sq = bql[j];
#pragma unroll
            for (int i = 0; i < 4; ++i) sq += hh[i] * wq[i * 4 + j];
            q2[j] = sq * LOG2E;
        }
    }
    __syncthreads();

    gather_tail(kv, su, q2, hh, l, Wo, bo, ln1_g, ln1_b, W1, b1, W2, b2, ln2_g, ln2_b);

    hout[(size_t)b * NN + own] = make_float4(hh[0], hh[1], hh[2], hh[3]);
}

// ============ K1: GAT layer 1, 2 blocks/graph ============
__global__ __launch_bounds__(1024) void gat_layer_kernel(
    const float4* __restrict__ hin, float4* __restrict__ hout,
    const int* __restrict__ src, const int l,
    const float* __restrict__ Wq, const float* __restrict__ bq,
    const float* __restrict__ Wk, const float* __restrict__ bk,
    const float* __restrict__ Wv, const float* __restrict__ bv,
    const float* __restrict__ Wo, const float* __restrict__ bo,
    const float* __restrict__ ln1_g, const float* __restrict__ ln1_b,
    const float* __restrict__ W1, const float* __restrict__ b1,
    const float* __restrict__ W2, const float* __restrict__ b2,
    const float* __restrict__ ln2_g, const float* __restrict__ ln2_b)
{
    __shared__ uint4 kv[NN];
    const int bid = blockIdx.x;
    const int b = bid >> 1, half = bid & 1;
    const int tid = threadIdx.x;
    const int own = half * 1024 + tid;

    int su[16];
    {
        const int4* sp = reinterpret_cast<const int4*>(src + own * DEG);
#pragma unroll
        for (int t4 = 0; t4 < 4; ++t4) {
            int4 s4 = sp[t4];
            su[t4 * 4 + 0] = s4.x; su[t4 * 4 + 1] = s4.y;
            su[t4 * 4 + 2] = s4.z; su[t4 * 4 + 3] = s4.w;
        }
    }

    const float4* hb = hin + (size_t)b * NN;
    float hv[2][4];
    {
        float4 a0 = hb[tid];
        float4 a1 = hb[1024 + tid];
        hv[0][0] = a0.x; hv[0][1] = a0.y; hv[0][2] = a0.z; hv[0][3] = a0.w;
        hv[1][0] = a1.x; hv[1][1] = a1.y; hv[1][2] = a1.z; hv[1][3] = a1.w;
    }

    const float* wk = Wk + l * 16; const float* bkl = bk + l * 4;
    const float* wv = Wv + l * 16; const float* bvl = bv + l * 4;
#pragma unroll
    for (int c = 0; c < 2; ++c) {
        float kk[4], vv[4];
#pragma unroll
        for (int j = 0; j < 4; ++j) {
            float sk = bkl[j], sv = bvl[j];
#pragma unroll
            for (int i = 0; i < 4; ++i) {
                sk += hv[c][i] * wk[i * 4 + j];
                sv += hv[c][i] * wv[i * 4 + j];
            }
            kk[j] = sk; vv[j] = sv;
        }
        kv[c * 1024 + tid] = make_uint4(pk_bf16(kk[0], kk[1]), pk_bf16(kk[2], kk[3]),
                                        pk_bf16(vv[0], vv[1]), pk_bf16(vv[2], vv[3]));
    }

    float hh[4] = {hv[half][0], hv[half][1], hv[half][2], hv[half][3]};
    float q2[4];
    {
        const float* wq = Wq + l * 16; const float* bql = bq + l * 4;
#pragma unroll
        for (int j = 0; j < 4; ++j) {
            float sq = bql[j];
#pragma unroll
            for (int i = 0; i < 4; ++i) sq += hh[i] * wq[i * 4 + j];
            q2[j] = sq * LOG2E;
        }
    }
    __syncthreads();

    gather_tail(kv, su, q2, hh, l, Wo, bo, ln1_g, ln1_b, W1, b1, W2, b2, ln2_g, ln2_b);

    hout[(size_t)b * NN + own] = make_float4(hh[0], hh[1], hh[2], hh[3]);
}

// ======== mlp1b: split-K fc1 obs-part, RPB batch rows per block ========
__global__ __launch_bounds__(256) void mlp1b_kernel(
    const float* __restrict__ obs, const float* __restrict__ oW1,
    float* __restrict__ partial)
{
    __shared__ float red[4][RPB][HID];
    const int blk = blockIdx.x;
    const int rg = blk >> 4;          // row group
    const int ks = blk & (KS - 1);
    const int tid = threadIdx.x;
    const int w = tid >> 6, lane = tid & 63;

    const int c0 = ks * CH;
    const int c1 = min(c0 + CH, OBSD);
    const int wl = (c1 - c0 + 3) >> 2;
    const int s0 = c0 + w * wl;
    const int s1 = min(s0 + wl, c1);
    const float* ob0 = obs + (size_t)(rg * RPB) * OBSD;

    if (lane < HID) {
        float acc[RPB] = {0.f, 0.f, 0.f, 0.f};
#pragma unroll 4
        for (int i = s0; i < s1; ++i) {
            float wv = oW1[(size_t)(i + 4) * HID + lane];
#pragma unroll
            for (int r = 0; r < RPB; ++r)
                acc[r] += ob0[(size_t)r * OBSD + i] * wv;
        }
#pragma unroll
        for (int r = 0; r < RPB; ++r) red[w][r][lane] = acc[r];
    }
    __syncthreads();
    for (int idx = tid; idx < RPB * HID; idx += 256) {
        const int r = idx / HID, j = idx % HID;
        partial[(size_t)((rg * RPB + r) * KS + ks) * HID + j] =
            red[0][r][j] + red[1][r][j] + red[2][r][j] + red[3][r][j];
    }
}

// ===== K3: layer 2 restricted to the agent cone + layer 3 + MLP head =====
// 1 block per graph. Stage kv2 (full graph), compute h3 only at the 17 needed
// nodes, then the agent's layer-3 attention and the MLP head.
__global__ __launch_bounds__(1024) void gat_l2final_kernel(
    const float4* __restrict__ hin /* h2 */, const int* __restrict__ src,
    const int* __restrict__ agent_nodes,
    const float* __restrict__ Wq, const float* __restrict__ bq,
    const float* __restrict__ Wk, const float* __restrict__ bk,
    const float* __restrict__ Wv, const float* __restrict__ bv,
    const float* __restrict__ Wo, const float* __restrict__ bo,
    const float* __restrict__ ln1_g, const float* __restrict__ ln1_b,
    const float* __restrict__ W1, const float* __restrict__ b1,
    const float* __restrict__ W2, const float* __restrict__ b2,
    const float* __restrict__ ln2_g, const float* __restrict__ ln2_b,
    const float* __restrict__ partial, const float* __restrict__ oW1,
    const float* __restrict__ ob1,
    const float* __restrict__ oW2, const float* __restrict__ ob2,
    const float* __restrict__ oW3, const float* __restrict__ ob3,
    float* __restrict__ out)
{
    __shared__ uint4 kv[NN];
    __shared__ float h3buf[17][4];
    __shared__ float hm1s[HID], hm2s[HID];
    const int b = blockIdx.x;
    const int tid = threadIdx.x;
    const int l = 2;
    const float4* hb = hin + (size_t)b * NN;

    // stage kv2 for the whole graph
    const float* wk = Wk + l * 16; const float* bkl = bk + l * 4;
    const float* wv = Wv + l * 16; const float* bvl = bv + l * 4;
#pragma unroll
    for (int c = 0; c < 2; ++c) {
        float4 a = hb[c * 1024 + tid];
        float hh0[4] = {a.x, a.y, a.z, a.w};
        float kk[4], vv[4];
#pragma unroll
        for (int j = 0; j < 4; ++j) {
            float sk = bkl[j], sv = bvl[j];
#pragma unroll
            for (int i = 0; i < 4; ++i) {
                sk += hh0[i] * wk[i * 4 + j];
                sv += hh0[i] * wv[i * 4 + j];
            }
            kk[j] = sk; vv[j] = sv;
        }
        kv[c * 1024 + tid] = make_uint4(pk_bf16(kk[0], kk[1]), pk_bf16(kk[2], kk[3]),
                                        pk_bf16(vv[0], vv[1]), pk_bf16(vv[2], vv[3]));
    }
    const int ag = agent_nodes[b];
    __syncthreads();

    // 17 L2 node-tails: lanes 0..15 -> agent's neighbors, lane 16 -> agent
    if (tid < 17) {
        const int node = (tid < 16) ? src[ag * DEG + tid] : ag;
        float4 hn4 = hb[node];
        float hh[4] = {hn4.x, hn4.y, hn4.z, hn4.w};
        float q2[4];
        {
            const float* wq = Wq + l * 16; const float* bql = bq + l * 4;
#pragma unroll
            for (int j = 0; j < 4; ++j) {
                float sq = bql[j];
#pragma unroll
                for (int i = 0; i < 4; ++i) sq += hh[i] * wq[i * 4 + j];
                q2[j] = sq * LOG2E;
            }
        }
        int su2[16];
        const int4* sp = reinterpret_cast<const int4*>(src + node * DEG);
#pragma unroll
        for (int t4 = 0; t4 < 4; ++t4) {
            int4 s4 = sp[t4];
            su2[t4 * 4 + 0] = s4.x; su2[t4 * 4 + 1] = s4.y;
            su2[t4 * 4 + 2] = s4.z; su2[t4 * 4 + 3] = s4.w;
        }
        gather_tail(kv, su2, q2, hh, l, Wo, bo, ln1_g, ln1_b, W1, b1, W2, b2,
                    ln2_g, ln2_b);
#pragma unroll
        for (int j = 0; j < 4; ++j) h3buf[tid][j] = hh[j];
    }
    __syncthreads();

    // wave 0: layer-3 attention at the agent node + fc1
    if (tid < 64) {
        const int e = tid >> 2, hd = tid & 3;
        const int l3 = NL - 1;
        float ha[4] = {h3buf[16][0], h3buf[16][1], h3buf[16][2], h3buf[16][3]};

        float qh;
        {
            const float* wq = Wq + l3 * 16;
            qh = bq[l3 * 4 + hd];
#pragma unroll
            for (int i = 0; i < 4; ++i) qh += ha[i] * wq[i * 4 + hd];
            qh *= LOG2E;
        }
        float kh, vh;
        {
            const float* wk3 = Wk + l3 * 16; const float* wv3 = Wv + l3 * 16;
            kh = bk[l3 * 4 + hd]; vh = bv[l3 * 4 + hd];
#pragma unroll
            for (int i = 0; i < 4; ++i) {
                kh += h3buf[e][i] * wk3[i * 4 + hd];
                vh += h3buf[e][i] * wv3[i * 4 + hd];
            }
        }
        float p = __builtin_amdgcn_exp2f(qh * kh);
        float z = p, wv_s = p * vh;
#pragma unroll
        for (int m = 4; m <= 32; m <<= 1) {
            z    += __shfl_xor(z, m, 64);
            wv_s += __shfl_xor(wv_s, m, 64);
        }
        float msg_h = wv_s * frcp(z + 1e-6f);
        float msg[4];
#pragma unroll
        for (int j = 0; j < 4; ++j) msg[j] = __shfl(msg_h, (tid & ~3) + j, 64);

        float hh[4] = {ha[0], ha[1], ha[2], ha[3]};
        node_tail(hh, msg, Wo + l3 * 16, bo + l3 * 4, ln1_g + l3 * 4, ln1_b + l3 * 4,
                  W1 + l3 * 32, b1 + l3 * 8, W2 + l3 * 32, b2 + l3 * 4,
                  ln2_g + l3 * 4, ln2_b + l3 * 4);

        if (tid < HID) {
            float s = ob1[tid];
            const float* pp = partial + (size_t)b * KS * HID + tid;
#pragma unroll
            for (int ks = 0; ks < KS; ++ks) s += pp[ks * HID];
#pragma unroll
            for (int k = 0; k < 4; ++k) s += hh[k] * oW1[k * HID + tid];
            hm1s[tid] = tanhf(s);
        }
    }
    __syncthreads();
    if (tid < HID) {
        float s = ob2[tid];
        for (int k = 0; k < HID; ++k) s += hm1s[k] * oW2[k * HID + tid];
        hm2s[tid] = tanhf(s);
    }
    __syncthreads();
    if (tid < NOUT) {
        float s = ob3[tid];
        for (int k = 0; k < HID; ++k) s += hm2s[k] * oW3[k * NOUT + tid];
        out[(size_t)b * NOUT + tid] = s;
    }
}

// ===================== fallback: one block per graph + split-K mlp =====================
__global__ __launch_bounds__(1024) void gat_single_kernel(
    const float* __restrict__ x, const int* __restrict__ src,
    const int* __restrict__ agent_nodes,
    const float* __restrict__ We, const float* __restrict__ be,
    const float* __restrict__ Wq, const float* __restrict__ bq,
    const float* __restrict__ Wk, const float* __restrict__ bk,
    const float* __restrict__ Wv, const float* __restrict__ bv,
    const float* __restrict__ Wo, const float* __restrict__ bo,
    const float* __restrict__ ln1_g, const float* __restrict__ ln1_b,
    const float* __restrict__ W1, const float* __restrict__ b1,
    const float* __restrict__ W2, const float* __restrict__ b2,
    const float* __restrict__ ln2_g, const float* __restrict__ ln2_b,
    float* __restrict__ gat_out)
{
    __shared__ uint4 kv[NN];
    const int b = blockIdx.x;
    const int tid = threadIdx.x;
    float h[2][4];
#pragma unroll
    for (int u = 0; u < 2; ++u) {
        const int n = tid + u * 1024;
        const float4* xr = reinterpret_cast<const float4*>(x + ((size_t)b * NN + n) * EMBD);
        float xv[16];
#pragma unroll
        for (int t4 = 0; t4 < 4; ++t4) {
            float4 t = xr[t4];
            xv[t4 * 4 + 0] = t.x; xv[t4 * 4 + 1] = t.y;
            xv[t4 * 4 + 2] = t.z; xv[t4 * 4 + 3] = t.w;
        }
#pragma unroll
        for (int j = 0; j < 4; ++j) {
            float s = be[j];
#pragma unroll
            for (int i = 0; i < 16; ++i) s += xv[i] * We[i * 4 + j];
            h[u][j] = s;
        }
    }
    for (int l = 0; l < NL; ++l) {
        float q2[2][4];
        const float* wq = Wq + l * 16; const float* bql = bq + l * 4;
        const float* wk = Wk + l * 16; const float* bkl = bk + l * 4;
        const float* wv = Wv + l * 16; const float* bvl = bv + l * 4;
#pragma unroll
        for (int u = 0; u < 2; ++u) {
            const int n = tid + u * 1024;
            float kk[4], vv[4];
#pragma unroll
            for (int j = 0; j < 4; ++j) {
                float sq = bql[j], sk = bkl[j], sv = bvl[j];
#pragma unroll
                for (int i = 0; i < 4; ++i) {
                    sq += h[u][i] * wq[i * 4 + j];
                    sk += h[u][i] * wk[i * 4 + j];
                    sv += h[u][i] * wv[i * 4 + j];
                }
                q2[u][j] = sq * LOG2E; kk[j] = sk; vv[j] = sv;
            }
            kv[n] = make_uint4(pk_bf16(kk[0], kk[1]), pk_bf16(kk[2], kk[3]),
                               pk_bf16(vv[0], vv[1]), pk_bf16(vv[2], vv[3]));
        }
        __syncthreads();
#pragma unroll
        for (int u = 0; u < 2; ++u) {
            const int n = tid + u * 1024;
            int su[16];
            const int4* sp = reinterpret_cast<const int4*>(src + n * DEG);
#pragma unroll
            for (int t4 = 0; t4 < 4; ++t4) {
                int4 s4 = sp[t4];
                su[t4 * 4 + 0] = s4.x; su[t4 * 4 + 1] = s4.y;
                su[t4 * 4 + 2] = s4.z; su[t4 * 4 + 3] = s4.w;
            }
            gather_tail(kv, su, q2[u], h[u], l, Wo, bo, ln1_g, ln1_b,
                        W1, b1, W2, b2, ln2_g, ln2_b);
        }
        __syncthreads();
    }
    const int agent = agent_nodes[b];
#pragma unroll
    for (int u = 0; u < 2; ++u) {
        if (tid + u * 1024 == agent) {
#pragma unroll
            for (int j = 0; j < 4; ++j) gat_out[b * 4 + j] = h[u][j];
        }
    }
}

__global__ __launch_bounds__(64) void mlp2_fb_kernel(
    const float* __restrict__ partial, const float* __restrict__ gat,
    const float* __restrict__ oW1, const float* __restrict__ ob1,
    const float* __restrict__ oW2, const float* __restrict__ ob2,
    const float* __restrict__ oW3, const float* __restrict__ ob3,
    float* __restrict__ out)
{
    __shared__ float hm1[HID], hm2[HID];
    const int b = blockIdx.x;
    const int tid = threadIdx.x;
    if (tid < HID) {
        float s = ob1[tid];
        const float* pp = partial + (size_t)b * KS * HID + tid;
#pragma unroll
        for (int ks = 0; ks < KS; ++ks) s += pp[ks * HID];
#pragma unroll
        for (int k = 0; k < 4; ++k) s += gat[b * 4 + k] * oW1[k * HID + tid];
        hm1[tid] = tanhf(s);
    }
    __syncthreads();
    if (tid < HID) {
        float s = ob2[tid];
        for (int k = 0; k < HID; ++k) s += hm1[k] * oW2[k * HID + tid];
        hm2[tid] = tanhf(s);
    }
    __syncthreads();
    if (tid < NOUT) {
        float s = ob3[tid];
        for (int k = 0; k < HID; ++k) s += hm2[k] * oW3[k * NOUT + tid];
        out[(size_t)b * NOUT + tid] = s;
    }
}

extern "C" void kernel_launch(void* const* d_in, const int* in_sizes, int n_in,
                              void* d_out, int out_size, void* d_ws, size_t ws_size,
                              hipStream_t stream) {
    const float* x      = (const float*)d_in[0];
    const float* obs    = (const float*)d_in[1];
    const int*   src    = (const int*)d_in[2];
    /* d_in[3] = dst: structurally repeat(arange(N), DEG) — not needed */
    const int*   agent  = (const int*)d_in[4];
    const float* We     = (const float*)d_in[5];
    const float* be     = (const float*)d_in[6];
    const float* Wq     = (const float*)d_in[7];
    const float* bq     = (const float*)d_in[8];
    const float* Wk     = (const float*)d_in[9];
    const float* bk     = (const float*)d_in[10];
    const float* Wv     = (const float*)d_in[11];
    const float* bv     = (const float*)d_in[12];
    const float* Wo     = (const float*)d_in[13];
    const float* bo     = (const float*)d_in[14];
    const float* ln1_g  = (const float*)d_in[15];
    const float* ln1_b  = (const float*)d_in[16];
    const float* W1     = (const float*)d_in[17];
    const float* b1     = (const float*)d_in[18];
    const float* W2     = (const float*)d_in[19];
    const float* b2     = (const float*)d_in[20];
    const float* ln2_g  = (const float*)d_in[21];
    const float* ln2_b  = (const float*)d_in[22];
    const float* oW1    = (const float*)d_in[23];
    const float* ob1    = (const float*)d_in[24];
    const float* oW2    = (const float*)d_in[25];
    const float* ob2    = (const float*)d_in[26];
    const float* oW3    = (const float*)d_in[27];
    const float* ob3    = (const float*)d_in[28];

    float* out = (float*)d_out;
    char*  ws  = (char*)d_ws;

    const size_t hbytes = (size_t)NB * NN * 16;          // 4 MiB
    const size_t need   = 2 * hbytes + 368640 + 4096;

    if (ws_size >= need) {
        float4* hA      = (float4*)ws;
        float4* hB      = (float4*)(ws + hbytes);
        float*  partial = (float*)(ws + 2 * hbytes);     // [128][16][45]

        mlp1b_kernel<<<(NB / RPB) * KS, 256, 0, stream>>>(obs, oW1, partial);

        gat_layer0_kernel<<<2 * NB, 1024, 0, stream>>>(x, hA, src,
            We, be, Wq, bq, Wk, bk, Wv, bv, Wo, bo, ln1_g, ln1_b, W1, b1, W2, b2,
            ln2_g, ln2_b);
        gat_layer_kernel<<<2 * NB, 1024, 0, stream>>>(hA, hB, src, 1,
            Wq, bq, Wk, bk, Wv, bv, Wo, bo, ln1_g, ln1_b, W1, b1, W2, b2, ln2_g, ln2_b);

        gat_l2final_kernel<<<NB, 1024, 0, stream>>>(hB, src, agent,
            Wq, bq, Wk, bk, Wv, bv, Wo, bo, ln1_g, ln1_b, W1, b1, W2, b2, ln2_g, ln2_b,
            partial, oW1, ob1, oW2, ob2, oW3, ob3, out);
    } else {
        float* gat_out = (float*)ws;
        float* partial = (float*)(ws + 2048);
        gat_single_kernel<<<NB, 1024, 0, stream>>>(x, src, agent, We, be, Wq, bq, Wk, bk,
                                                   Wv, bv, Wo, bo, ln1_g, ln1_b, W1, b1,
                                                   W2, b2, ln2_g, ln2_b, gat_out);
        mlp1b_kernel<<<(NB / RPB) * KS, 256, 0, stream>>>(obs, oW1, partial);
        mlp2_fb_kernel<<<NB, 64, 0, stream>>>(partial, gat_out, oW1, ob1, oW2, ob2,
                                              oW3, ob3, out);
    }
}

// Round 10
// 38.782 us; speedup vs baseline: 1.9561x; 1.1376x over previous
//
#include <hip/hip_runtime.h>
#include <hip/hip_bf16.h>

#define NB 128
#define NN 2048
#define DEG 16
#define EMBD 16
#define NL 4
#define OBSD 6154
#define HID 45
#define NOUT 15
#define KS 16
#define CH 385   // ceil(OBSD / KS)
#define RPB 4    // batch rows per mlp1 block
#define LOG2E 1.44269504f
#define MLPB ((NB / RPB) * KS)   // 512 mlp blocks in fused K1

__device__ __forceinline__ float frcp(float v) { return __builtin_amdgcn_rcpf(v); }

__device__ __forceinline__ uint32_t pk_bf16(float a, float b) {
    uint32_t ua = __float_as_uint(a); ua += 0x7fffu + ((ua >> 16) & 1u);
    uint32_t ub = __float_as_uint(b); ub += 0x7fffu + ((ub >> 16) & 1u);
    return (ua >> 16) | (ub & 0xffff0000u);
}
__device__ __forceinline__ float lo_bf(uint32_t u) { return __uint_as_float(u << 16); }
__device__ __forceinline__ float hi_bf(uint32_t u) { return __uint_as_float(u & 0xffff0000u); }

__device__ __forceinline__ void ln4(const float* p, const float* g, const float* bb, float* o) {
    float m = 0.25f * (p[0] + p[1] + p[2] + p[3]);
    float var = 0.f;
#pragma unroll
    for (int j = 0; j < 4; ++j) { float d = p[j] - m; var += d * d; }
    var *= 0.25f;
    float rs = rsqrtf(var + 1e-5f);
#pragma unroll
    for (int j = 0; j < 4; ++j) o[j] = g[j] * (p[j] - m) * rs + bb[j];
}

__device__ __forceinline__ void node_tail(float* hh, const float* msg,
    const float* wo, const float* bol, const float* g1, const float* be1,
    const float* w1, const float* b1l, const float* w2, const float* b2l,
    const float* g2, const float* be2)
{
    float pre[4];
#pragma unroll
    for (int j = 0; j < 4; ++j) {
        float s = bol[j];
#pragma unroll
        for (int i = 0; i < 4; ++i) s += msg[i] * wo[i * 4 + j];
        pre[j] = hh[j] + s;
    }
    float hn[4];
    ln4(pre, g1, be1, hn);
    float mid[8];
#pragma unroll
    for (int j = 0; j < 8; ++j) {
        float s = b1l[j];
#pragma unroll
        for (int i = 0; i < 4; ++i) s += hn[i] * w1[i * 8 + j];
        mid[j] = fmaxf(s, 0.f);
    }
    float pre2[4];
#pragma unroll
    for (int j = 0; j < 4; ++j) {
        float s = b2l[j];
#pragma unroll
        for (int i = 0; i < 8; ++i) s += mid[i] * w2[i * 4 + j];
        pre2[j] = hn[j] + s;
    }
    ln4(pre2, g2, be2, hh);
}

__device__ __forceinline__ uint4 kv_pack(const float* hh,
    const float* wk, const float* bkl, const float* wv, const float* bvl)
{
    float kk[4], vv[4];
#pragma unroll
    for (int j = 0; j < 4; ++j) {
        float sk = bkl[j], sv = bvl[j];
#pragma unroll
        for (int i = 0; i < 4; ++i) {
            sk += hh[i] * wk[i * 4 + j];
            sv += hh[i] * wv[i * 4 + j];
        }
        kk[j] = sk; vv[j] = sv;
    }
    return make_uint4(pk_bf16(kk[0], kk[1]), pk_bf16(kk[2], kk[3]),
                      pk_bf16(vv[0], vv[1]), pk_bf16(vv[2], vv[3]));
}

// shared gather + tail body for a layer (kv staged in LDS, q2 prescaled)
__device__ __forceinline__ void gather_tail(const uint4* kv, const int* su,
    const float* q2, float* hh, int l,
    const float* Wo, const float* bo, const float* ln1_g, const float* ln1_b,
    const float* W1, const float* b1, const float* W2, const float* b2,
    const float* ln2_g, const float* ln2_b)
{
    float z[4] = {0.f, 0.f, 0.f, 0.f}, wa[4] = {0.f, 0.f, 0.f, 0.f};
#pragma unroll
    for (int eb = 0; eb < 4; ++eb) {
        uint4 t0 = kv[su[eb * 4 + 0]];
        uint4 t1 = kv[su[eb * 4 + 1]];
        uint4 t2 = kv[su[eb * 4 + 2]];
        uint4 t3 = kv[su[eb * 4 + 3]];
        float p;
        p = __builtin_amdgcn_exp2f(q2[0] * lo_bf(t0.x)); z[0] += p; wa[0] += p * lo_bf(t0.z);
        p = __builtin_amdgcn_exp2f(q2[1] * hi_bf(t0.x)); z[1] += p; wa[1] += p * hi_bf(t0.z);
        p = __builtin_amdgcn_exp2f(q2[2] * lo_bf(t0.y)); z[2] += p; wa[2] += p * lo_bf(t0.w);
        p = __builtin_amdgcn_exp2f(q2[3] * hi_bf(t0.y)); z[3] += p; wa[3] += p * hi_bf(t0.w);
        p = __builtin_amdgcn_exp2f(q2[0] * lo_bf(t1.x)); z[0] += p; wa[0] += p * lo_bf(t1.z);
        p = __builtin_amdgcn_exp2f(q2[1] * hi_bf(t1.x)); z[1] += p; wa[1] += p * hi_bf(t1.z);
        p = __builtin_amdgcn_exp2f(q2[2] * lo_bf(t1.y)); z[2] += p; wa[2] += p * lo_bf(t1.w);
        p = __builtin_amdgcn_exp2f(q2[3] * hi_bf(t1.y)); z[3] += p; wa[3] += p * hi_bf(t1.w);
        p = __builtin_amdgcn_exp2f(q2[0] * lo_bf(t2.x)); z[0] += p; wa[0] += p * lo_bf(t2.z);
        p = __builtin_amdgcn_exp2f(q2[1] * hi_bf(t2.x)); z[1] += p; wa[1] += p * hi_bf(t2.z);
        p = __builtin_amdgcn_exp2f(q2[2] * lo_bf(t2.y)); z[2] += p; wa[2] += p * lo_bf(t2.w);
        p = __builtin_amdgcn_exp2f(q2[3] * hi_bf(t2.y)); z[3] += p; wa[3] += p * hi_bf(t2.w);
        p = __builtin_amdgcn_exp2f(q2[0] * lo_bf(t3.x)); z[0] += p; wa[0] += p * lo_bf(t3.z);
        p = __builtin_amdgcn_exp2f(q2[1] * hi_bf(t3.x)); z[1] += p; wa[1] += p * hi_bf(t3.z);
        p = __builtin_amdgcn_exp2f(q2[2] * lo_bf(t3.y)); z[2] += p; wa[2] += p * lo_bf(t3.w);
        p = __builtin_amdgcn_exp2f(q2[3] * hi_bf(t3.y)); z[3] += p; wa[3] += p * hi_bf(t3.w);
    }
    float msg[4];
#pragma unroll
    for (int j = 0; j < 4; ++j) msg[j] = wa[j] * frcp(z[j] + 1e-6f);
    node_tail(hh, msg, Wo + l * 16, bo + l * 4, ln1_g + l * 4, ln1_b + l * 4,
              W1 + l * 32, b1 + l * 8, W2 + l * 32, b2 + l * 4,
              ln2_g + l * 4, ln2_b + l * 4);
}

// ===== K1: blocks [0,512): mlp1 split-K; blocks [512,1536): embed + kv0 proj =====
__global__ __launch_bounds__(256) void mlp_embed_kernel(
    const float* __restrict__ obs, const float* __restrict__ oW1,
    float* __restrict__ partial,
    const float* __restrict__ x,
    const float* __restrict__ We, const float* __restrict__ be,
    const float* __restrict__ Wk, const float* __restrict__ bk,
    const float* __restrict__ Wv, const float* __restrict__ bv,
    float4* __restrict__ h0g, uint4* __restrict__ kv0g)
{
    const int bid = blockIdx.x;
    const int tid = threadIdx.x;

    if (bid < MLPB) {
        // ---------------- mlp1b ----------------
        __shared__ float red[4][RPB][HID];
        const int rg = bid >> 4;
        const int ks = bid & (KS - 1);
        const int w = tid >> 6, lane = tid & 63;
        const int c0 = ks * CH;
        const int c1 = min(c0 + CH, OBSD);
        const int wl = (c1 - c0 + 3) >> 2;
        const int s0 = c0 + w * wl;
        const int s1 = min(s0 + wl, c1);
        const float* ob0 = obs + (size_t)(rg * RPB) * OBSD;

        if (lane < HID) {
            float acc[RPB] = {0.f, 0.f, 0.f, 0.f};
#pragma unroll 4
            for (int i = s0; i < s1; ++i) {
                float wv = oW1[(size_t)(i + 4) * HID + lane];
#pragma unroll
                for (int r = 0; r < RPB; ++r)
                    acc[r] += ob0[(size_t)r * OBSD + i] * wv;
            }
#pragma unroll
            for (int r = 0; r < RPB; ++r) red[w][r][lane] = acc[r];
        }
        __syncthreads();
        for (int idx = tid; idx < RPB * HID; idx += 256) {
            const int r = idx / HID, j = idx % HID;
            partial[(size_t)((rg * RPB + r) * KS + ks) * HID + j] =
                red[0][r][j] + red[1][r][j] + red[2][r][j] + red[3][r][j];
        }
        return;
    }

    // ---------------- embed + layer-0 kv projection ----------------
    const int n = (bid - MLPB) * 256 + tid;   // < NB*NN
    const float4* xr = reinterpret_cast<const float4*>(x + (size_t)n * EMBD);
    float xv[16];
#pragma unroll
    for (int t4 = 0; t4 < 4; ++t4) {
        float4 t = xr[t4];
        xv[t4 * 4 + 0] = t.x; xv[t4 * 4 + 1] = t.y;
        xv[t4 * 4 + 2] = t.z; xv[t4 * 4 + 3] = t.w;
    }
    float hh[4];
#pragma unroll
    for (int j = 0; j < 4; ++j) {
        float s = be[j];
#pragma unroll
        for (int i = 0; i < 16; ++i) s += xv[i] * We[i * 4 + j];
        hh[j] = s;
    }
    h0g[n] = make_float4(hh[0], hh[1], hh[2], hh[3]);
    kv0g[n] = kv_pack(hh, Wk, bk, Wv, bv);   // layer-0 weights
}

// ===== K2: GAT layer 0. 4 blocks/graph, copy-only kv staging =====
__global__ __launch_bounds__(512, 8) void gat_layer0_kernel(
    const float4* __restrict__ h0g, const uint4* __restrict__ kv0g,
    float4* __restrict__ h1g, const int* __restrict__ src,
    const float* __restrict__ Wq, const float* __restrict__ bq,
    const float* __restrict__ Wo, const float* __restrict__ bo,
    const float* __restrict__ ln1_g, const float* __restrict__ ln1_b,
    const float* __restrict__ W1, const float* __restrict__ b1,
    const float* __restrict__ W2, const float* __restrict__ b2,
    const float* __restrict__ ln2_g, const float* __restrict__ ln2_b)
{
    __shared__ uint4 kv[NN];
    const int bid = blockIdx.x;
    const int b = bid >> 2, qd = bid & 3;
    const int tid = threadIdx.x;
    const int own = qd * 512 + tid;
    const int l = 0;

    const uint4* slab = kv0g + (size_t)b * NN;
#pragma unroll
    for (int c = 0; c < 4; ++c) kv[c * 512 + tid] = slab[c * 512 + tid];

    int su[16];
    {
        const int4* sp = reinterpret_cast<const int4*>(src + own * DEG);
#pragma unroll
        for (int t4 = 0; t4 < 4; ++t4) {
            int4 s4 = sp[t4];
            su[t4 * 4 + 0] = s4.x; su[t4 * 4 + 1] = s4.y;
            su[t4 * 4 + 2] = s4.z; su[t4 * 4 + 3] = s4.w;
        }
    }

    float4 h4 = h0g[(size_t)b * NN + own];
    float hh[4] = {h4.x, h4.y, h4.z, h4.w};
    float q2[4];
    {
        const float* wq = Wq + l * 16; const float* bql = bq + l * 4;
#pragma unroll
        for (int j = 0; j < 4; ++j) {
            float sq = bql[j];
#pragma unroll
            for (int i = 0; i < 4; ++i) sq += hh[i] * wq[i * 4 + j];
            q2[j] = sq * LOG2E;
        }
    }
    __syncthreads();

    gather_tail(kv, su, q2, hh, l, Wo, bo, ln1_g, ln1_b, W1, b1, W2, b2, ln2_g, ln2_b);

    h1g[(size_t)b * NN + own] = make_float4(hh[0], hh[1], hh[2], hh[3]);
}

// ===== K3: L1 cone tails + L2 on-demand + L3 + MLP head. 1 block/graph =====
__global__ __launch_bounds__(1024) void gat_conefinal_kernel(
    const float4* __restrict__ h1g, const int* __restrict__ src,
    const int* __restrict__ agent_nodes,
    const float* __restrict__ Wq, const float* __restrict__ bq,
    const float* __restrict__ Wk, const float* __restrict__ bk,
    const float* __restrict__ Wv, const float* __restrict__ bv,
    const float* __restrict__ Wo, const float* __restrict__ bo,
    const float* __restrict__ ln1_g, const float* __restrict__ ln1_b,
    const float* __restrict__ W1, const float* __restrict__ b1,
    const float* __restrict__ W2, const float* __restrict__ b2,
    const float* __restrict__ ln2_g, const float* __restrict__ ln2_b,
    const float* __restrict__ partial, const float* __restrict__ oW1,
    const float* __restrict__ ob1,
    const float* __restrict__ oW2, const float* __restrict__ ob2,
    const float* __restrict__ oW3, const float* __restrict__ ob3,
    float* __restrict__ out)
{
    __shared__ uint4 kv[NN];          // kv1 (layer-1)
    __shared__ float h2c[289][4];     // cone h2: slots 0..16 = C2, 17+i*16+e = N(C2)
    __shared__ int   conen[289];
    __shared__ float h3buf[17][4];
    __shared__ float hm1s[HID], hm2s[HID];
    const int b = blockIdx.x;
    const int tid = threadIdx.x;
    const int l1 = 1, l2 = 2, l3 = 3;
    const float4* hb = h1g + (size_t)b * NN;
    const int ag = agent_nodes[b];

    // stage kv1 for the whole graph (2 nodes/thread, no duplication)
    {
        const float* wk = Wk + l1 * 16; const float* bkl = bk + l1 * 4;
        const float* wv = Wv + l1 * 16; const float* bvl = bv + l1 * 4;
#pragma unroll
        for (int c = 0; c < 2; ++c) {
            float4 a = hb[c * 1024 + tid];
            float hh0[4] = {a.x, a.y, a.z, a.w};
            kv[c * 1024 + tid] = kv_pack(hh0, wk, bkl, wv, bvl);
        }
    }
    // cone node list (independent of kv)
    if (tid < 17)  conen[tid] = (tid < 16) ? src[ag * DEG + tid] : ag;
    if (tid < 272) {
        const int i = tid >> 4, e = tid & 15;
        const int ti = (i < 16) ? src[ag * DEG + i] : ag;
        conen[17 + tid] = src[ti * DEG + e];
    }
    __syncthreads();

    // L1 tails at the 289 cone slots
    if (tid < 289) {
        const int node = conen[tid];
        float4 hn4 = hb[node];
        float hh[4] = {hn4.x, hn4.y, hn4.z, hn4.w};
        float q2[4];
        {
            const float* wq = Wq + l1 * 16; const float* bql = bq + l1 * 4;
#pragma unroll
            for (int j = 0; j < 4; ++j) {
                float sq = bql[j];
#pragma unroll
                for (int i = 0; i < 4; ++i) sq += hh[i] * wq[i * 4 + j];
                q2[j] = sq * LOG2E;
            }
        }
        int su2[16];
        const int4* sp = reinterpret_cast<const int4*>(src + node * DEG);
#pragma unroll
        for (int t4 = 0; t4 < 4; ++t4) {
            int4 s4 = sp[t4];
            su2[t4 * 4 + 0] = s4.x; su2[t4 * 4 + 1] = s4.y;
            su2[t4 * 4 + 2] = s4.z; su2[t4 * 4 + 3] = s4.w;
        }
        gather_tail(kv, su2, q2, hh, l1, Wo, bo, ln1_g, ln1_b, W1, b1, W2, b2,
                    ln2_g, ln2_b);
#pragma unroll
        for (int j = 0; j < 4; ++j) h2c[tid][j] = hh[j];
    }
    __syncthreads();

    // L2 tails for the 17 C2 nodes: thread (i,e), on-demand f32 k/v projection
    if (tid < 272) {
        const int i = tid >> 4, e = tid & 15;
        float q2[4];
        {
            const float* wq = Wq + l2 * 16; const float* bql = bq + l2 * 4;
#pragma unroll
            for (int j = 0; j < 4; ++j) {
                float sq = bql[j];
#pragma unroll
                for (int k = 0; k < 4; ++k) sq += h2c[i][k] * wq[k * 4 + j];
                q2[j] = sq * LOG2E;
            }
        }
        const float* hnb = h2c[17 + tid];
        float z[4], pv[4];
        {
            const float* wk = Wk + l2 * 16; const float* bkl = bk + l2 * 4;
            const float* wv = Wv + l2 * 16; const float* bvl = bv + l2 * 4;
#pragma unroll
            for (int j = 0; j < 4; ++j) {
                float kh = bkl[j], vh = bvl[j];
#pragma unroll
                for (int k = 0; k < 4; ++k) {
                    kh += hnb[k] * wk[k * 4 + j];
                    vh += hnb[k] * wv[k * 4 + j];
                }
                float p = __builtin_amdgcn_exp2f(q2[j] * kh);
                z[j] = p; pv[j] = p * vh;
            }
        }
#pragma unroll
        for (int m = 1; m <= 8; m <<= 1) {
#pragma unroll
            for (int j = 0; j < 4; ++j) {
                z[j]  += __shfl_xor(z[j], m, 64);
                pv[j] += __shfl_xor(pv[j], m, 64);
            }
        }
        if (e == 0) {
            float msg[4];
#pragma unroll
            for (int j = 0; j < 4; ++j) msg[j] = pv[j] * frcp(z[j] + 1e-6f);
            float hh[4] = {h2c[i][0], h2c[i][1], h2c[i][2], h2c[i][3]};
            node_tail(hh, msg, Wo + l2 * 16, bo + l2 * 4, ln1_g + l2 * 4, ln1_b + l2 * 4,
                      W1 + l2 * 32, b1 + l2 * 8, W2 + l2 * 32, b2 + l2 * 4,
                      ln2_g + l2 * 4, ln2_b + l2 * 4);
#pragma unroll
            for (int j = 0; j < 4; ++j) h3buf[i][j] = hh[j];
        }
    }
    __syncthreads();

    // L3 at the agent + fc1 (wave 0)
    if (tid < 64) {
        const int e = tid >> 2, hd = tid & 3;
        float ha[4] = {h3buf[16][0], h3buf[16][1], h3buf[16][2], h3buf[16][3]};
        float qh;
        {
            const float* wq = Wq + l3 * 16;
            qh = bq[l3 * 4 + hd];
#pragma unroll
            for (int i = 0; i < 4; ++i) qh += ha[i] * wq[i * 4 + hd];
            qh *= LOG2E;
        }
        float kh, vh;
        {
            const float* wk3 = Wk + l3 * 16; const float* wv3 = Wv + l3 * 16;
            kh = bk[l3 * 4 + hd]; vh = bv[l3 * 4 + hd];
#pragma unroll
            for (int i = 0; i < 4; ++i) {
                kh += h3buf[e][i] * wk3[i * 4 + hd];
                vh += h3buf[e][i] * wv3[i * 4 + hd];
            }
        }
        float p = __builtin_amdgcn_exp2f(qh * kh);
        float z = p, wv_s = p * vh;
#pragma unroll
        for (int m = 4; m <= 32; m <<= 1) {
            z    += __shfl_xor(z, m, 64);
            wv_s += __shfl_xor(wv_s, m, 64);
        }
        float msg_h = wv_s * frcp(z + 1e-6f);
        float msg[4];
#pragma unroll
        for (int j = 0; j < 4; ++j) msg[j] = __shfl(msg_h, (tid & ~3) + j, 64);

        float hh[4] = {ha[0], ha[1], ha[2], ha[3]};
        node_tail(hh, msg, Wo + l3 * 16, bo + l3 * 4, ln1_g + l3 * 4, ln1_b + l3 * 4,
                  W1 + l3 * 32, b1 + l3 * 8, W2 + l3 * 32, b2 + l3 * 4,
                  ln2_g + l3 * 4, ln2_b + l3 * 4);

        if (tid < HID) {
            float s = ob1[tid];
            const float* pp = partial + (size_t)b * KS * HID + tid;
#pragma unroll
            for (int ks = 0; ks < KS; ++ks) s += pp[ks * HID];
#pragma unroll
            for (int k = 0; k < 4; ++k) s += hh[k] * oW1[k * HID + tid];
            hm1s[tid] = tanhf(s);
        }
    }
    __syncthreads();
    if (tid < HID) {
        float s = ob2[tid];
        for (int k = 0; k < HID; ++k) s += hm1s[k] * oW2[k * HID + tid];
        hm2s[tid] = tanhf(s);
    }
    __syncthreads();
    if (tid < NOUT) {
        float s = ob3[tid];
        for (int k = 0; k < HID; ++k) s += hm2s[k] * oW3[k * NOUT + tid];
        out[(size_t)b * NOUT + tid] = s;
    }
}

// ===================== fallback: one block per graph + split-K mlp =====================
__global__ __launch_bounds__(1024) void gat_single_kernel(
    const float* __restrict__ x, const int* __restrict__ src,
    const int* __restrict__ agent_nodes,
    const float* __restrict__ We, const float* __restrict__ be,
    const float* __restrict__ Wq, const float* __restrict__ bq,
    const float* __restrict__ Wk, const float* __restrict__ bk,
    const float* __restrict__ Wv, const float* __restrict__ bv,
    const float* __restrict__ Wo, const float* __restrict__ bo,
    const float* __restrict__ ln1_g, const float* __restrict__ ln1_b,
    const float* __restrict__ W1, const float* __restrict__ b1,
    const float* __restrict__ W2, const float* __restrict__ b2,
    const float* __restrict__ ln2_g, const float* __restrict__ ln2_b,
    float* __restrict__ gat_out)
{
    __shared__ uint4 kv[NN];
    const int b = blockIdx.x;
    const int tid = threadIdx.x;
    float h[2][4];
#pragma unroll
    for (int u = 0; u < 2; ++u) {
        const int n = tid + u * 1024;
        const float4* xr = reinterpret_cast<const float4*>(x + ((size_t)b * NN + n) * EMBD);
        float xv[16];
#pragma unroll
        for (int t4 = 0; t4 < 4; ++t4) {
            float4 t = xr[t4];
            xv[t4 * 4 + 0] = t.x; xv[t4 * 4 + 1] = t.y;
            xv[t4 * 4 + 2] = t.z; xv[t4 * 4 + 3] = t.w;
        }
#pragma unroll
        for (int j = 0; j < 4; ++j) {
            float s = be[j];
#pragma unroll
            for (int i = 0; i < 16; ++i) s += xv[i] * We[i * 4 + j];
            h[u][j] = s;
        }
    }
    for (int l = 0; l < NL; ++l) {
        float q2[2][4];
        const float* wq = Wq + l * 16; const float* bql = bq + l * 4;
        const float* wk = Wk + l * 16; const float* bkl = bk + l * 4;
        const float* wv = Wv + l * 16; const float* bvl = bv + l * 4;
#pragma unroll
        for (int u = 0; u < 2; ++u) {
            const int n = tid + u * 1024;
#pragma unroll
            for (int j = 0; j < 4; ++j) {
                float sq = bql[j];
#pragma unroll
                for (int i = 0; i < 4; ++i) sq += h[u][i] * wq[i * 4 + j];
                q2[u][j] = sq * LOG2E;
            }
            kv[n] = kv_pack(h[u], wk, bkl, wv, bvl);
        }
        __syncthreads();
#pragma unroll
        for (int u = 0; u < 2; ++u) {
            const int n = tid + u * 1024;
            int su[16];
            const int4* sp = reinterpret_cast<const int4*>(src + n * DEG);
#pragma unroll
            for (int t4 = 0; t4 < 4; ++t4) {
                int4 s4 = sp[t4];
                su[t4 * 4 + 0] = s4.x; su[t4 * 4 + 1] = s4.y;
                su[t4 * 4 + 2] = s4.z; su[t4 * 4 + 3] = s4.w;
            }
            gather_tail(kv, su, q2[u], h[u], l, Wo, bo, ln1_g, ln1_b,
                        W1, b1, W2, b2, ln2_g, ln2_b);
        }
        __syncthreads();
    }
    const int agent = agent_nodes[b];
#pragma unroll
    for (int u = 0; u < 2; ++u) {
        if (tid + u * 1024 == agent) {
#pragma unroll
            for (int j = 0; j < 4; ++j) gat_out[b * 4 + j] = h[u][j];
        }
    }
}

__global__ __launch_bounds__(64) void mlp2_fb_kernel(
    const float* __restrict__ partial, const float* __restrict__ gat,
    const float* __restrict__ oW1, const float* __restrict__ ob1,
    const float* __restrict__ oW2, const float* __restrict__ ob2,
    const float* __restrict__ oW3, const float* __restrict__ ob3,
    float* __restrict__ out)
{
    __shared__ float hm1[HID], hm2[HID];
    const int b = blockIdx.x;
    const int tid = threadIdx.x;
    if (tid < HID) {
        float s = ob1[tid];
        const float* pp = partial + (size_t)b * KS * HID + tid;
#pragma unroll
        for (int ks = 0; ks < KS; ++ks) s += pp[ks * HID];
#pragma unroll
        for (int k = 0; k < 4; ++k) s += gat[b * 4 + k] * oW1[k * HID + tid];
        hm1[tid] = tanhf(s);
    }
    __syncthreads();
    if (tid < HID) {
        float s = ob2[tid];
        for (int k = 0; k < HID; ++k) s += hm1[k] * oW2[k * HID + tid];
        hm2[tid] = tanhf(s);
    }
    __syncthreads();
    if (tid < NOUT) {
        float s = ob3[tid];
        for (int k = 0; k < HID; ++k) s += hm2[k] * oW3[k * NOUT + tid];
        out[(size_t)b * NOUT + tid] = s;
    }
}

extern "C" void kernel_launch(void* const* d_in, const int* in_sizes, int n_in,
                              void* d_out, int out_size, void* d_ws, size_t ws_size,
                              hipStream_t stream) {
    const float* x      = (const float*)d_in[0];
    const float* obs    = (const float*)d_in[1];
    const int*   src    = (const int*)d_in[2];
    /* d_in[3] = dst: structurally repeat(arange(N), DEG) — not needed */
    const int*   agent  = (const int*)d_in[4];
    const float* We     = (const float*)d_in[5];
    const float* be     = (const float*)d_in[6];
    const float* Wq     = (const float*)d_in[7];
    const float* bq     = (const float*)d_in[8];
    const float* Wk     = (const float*)d_in[9];
    const float* bk     = (const float*)d_in[10];
    const float* Wv     = (const float*)d_in[11];
    const float* bv     = (const float*)d_in[12];
    const float* Wo     = (const float*)d_in[13];
    const float* bo     = (const float*)d_in[14];
    const float* ln1_g  = (const float*)d_in[15];
    const float* ln1_b  = (const float*)d_in[16];
    const float* W1     = (const float*)d_in[17];
    const float* b1     = (const float*)d_in[18];
    const float* W2     = (const float*)d_in[19];
    const float* b2     = (const float*)d_in[20];
    const float* ln2_g  = (const float*)d_in[21];
    const float* ln2_b  = (const float*)d_in[22];
    const float* oW1    = (const float*)d_in[23];
    const float* ob1    = (const float*)d_in[24];
    const float* oW2    = (const float*)d_in[25];
    const float* ob2    = (const float*)d_in[26];
    const float* oW3    = (const float*)d_in[27];
    const float* ob3    = (const float*)d_in[28];

    float* out = (float*)d_out;
    char*  ws  = (char*)d_ws;

    const size_t hbytes  = (size_t)NB * NN * 16;         // 4 MiB
    const size_t kvbytes = (size_t)NB * NN * 16;         // 4 MiB (uint4/node)
    const size_t need    = 2 * hbytes + kvbytes + 368640 + 4096;

    if (ws_size >= need) {
        float4* h0g     = (float4*)ws;
        float4* h1g     = (float4*)(ws + hbytes);
        uint4*  kv0g    = (uint4*)(ws + 2 * hbytes);
        float*  partial = (float*)(ws + 2 * hbytes + kvbytes);   // [128][16][45]

        mlp_embed_kernel<<<MLPB + NB * NN / 256, 256, 0, stream>>>(
            obs, oW1, partial, x, We, be, Wk, bk, Wv, bv, h0g, kv0g);

        gat_layer0_kernel<<<4 * NB, 512, 0, stream>>>(h0g, kv0g, h1g, src,
            Wq, bq, Wo, bo, ln1_g, ln1_b, W1, b1, W2, b2, ln2_g, ln2_b);

        gat_conefinal_kernel<<<NB, 1024, 0, stream>>>(h1g, src, agent,
            Wq, bq, Wk, bk, Wv, bv, Wo, bo, ln1_g, ln1_b, W1, b1, W2, b2, ln2_g, ln2_b,
            partial, oW1, ob1, oW2, ob2, oW3, ob3, out);
    } else {
        float* gat_out = (float*)ws;
        float* partial = (float*)(ws + 2048);
        gat_single_kernel<<<NB, 1024, 0, stream>>>(x, src, agent, We, be, Wq, bq, Wk, bk,
                                                   Wv, bv, Wo, bo, ln1_g, ln1_b, W1, b1,
                                                   W2, b2, ln2_g, ln2_b, gat_out);
        mlp_embed_kernel<<<MLPB, 256, 0, stream>>>(
            obs, oW1, partial, x, We, be, Wk, bk, Wv, bv,
            (float4*)(ws + 2048 + 368640), (uint4*)(ws + 2048 + 368640));
        mlp2_fb_kernel<<<NB, 64, 0, stream>>>(partial, gat_out, oW1, ob1, oW2, ob2,
                                              oW3, ob3, out);
    }
}